// Round 2
// baseline (1190.469 us; speedup 1.0000x reference)
//
#include <hip/hip_runtime.h>
#include <math.h>

// Problem constants
#define BATCH 4
#define SEQ   1024
#define DIM   1024
#define HEADS 16
#define HD    64
#define NEXP  2
#define NSLOT 512
#define ES    1024       // NEXP*NSLOT
#define HID   4096
#define LNEPS 1e-5f
#define NTOK  (BATCH*SEQ)

typedef long long ll;
typedef unsigned short ushort;
typedef unsigned int uint;
typedef __attribute__((ext_vector_type(8))) short short8;   // 8 bf16 (4 VGPRs)
typedef __attribute__((ext_vector_type(4))) float f32x4;    // MFMA accum
typedef __attribute__((ext_vector_type(4))) unsigned short us4;

__device__ __forceinline__ ushort f2b(float f) {            // fp32 -> bf16 RNE
    uint u = __builtin_bit_cast(uint, f);
    u += 0x7FFFu + ((u >> 16) & 1u);
    return (ushort)(u >> 16);
}
__device__ __forceinline__ float b2f(ushort h) {
    uint u = ((uint)h) << 16;
    return __builtin_bit_cast(float, u);
}
__device__ __forceinline__ uint pk(float a, float b) {
    return (uint)f2b(a) | ((uint)f2b(b) << 16);
}
__device__ __forceinline__ float gelu_f(float v) {
    float x3 = v * v * v;
    return 0.5f * v * (1.f + tanhf(0.7978845608028654f * (v + 0.044715f * x3)));
}

// async global->LDS, 16B per lane.  LDS dest must be wave-uniform base + lane*16.
__device__ __forceinline__ void gload16(const ushort* g, ushort* l) {
    __builtin_amdgcn_global_load_lds(
        (const __attribute__((address_space(1))) unsigned int*)(const void*)g,
        (__attribute__((address_space(3))) unsigned int*)(void*)l,
        16, 0, 0);
}

// ---------------------------------------------------------------------------
// fp32 -> bf16 elementwise convert, 8 elems/thread (x: 4M elems, grid 2048)
// ---------------------------------------------------------------------------
__global__ __launch_bounds__(256) void cvt_bf16(
    const float* __restrict__ src, ushort* __restrict__ dst)
{
    int i = blockIdx.x * 256 + threadIdx.x;
    const float4* s = reinterpret_cast<const float4*>(src) + (ll)i * 2;
    float4 a = s[0], b = s[1];
    uint4 w;
    w.x = pk(a.x, a.y); w.y = pk(a.z, a.w);
    w.z = pk(b.x, b.y); w.w = pk(b.z, b.w);
    reinterpret_cast<uint4*>(dst)[i] = w;
}

// bias concat: o[0..1023] = a, o[1024..3071] = b   (grid 12)
__global__ __launch_bounds__(256) void concat_bias(
    const float* __restrict__ a, const float* __restrict__ b,
    float* __restrict__ o)
{
    int i = blockIdx.x * 256 + threadIdx.x;
    o[i] = (i < DIM) ? a[i] : b[i - DIM];
}

// ---------------------------------------------------------------------------
// Tiled transpose(+convert): dst[c][r] = bf16(src[r][c]).  64x64 tiles.
// grid (ncol/64, nrow/64, Z); z = z1*Z2+z2 with per-operand stride pairs.
// ---------------------------------------------------------------------------
template<typename TS>
__global__ __launch_bounds__(256) void transpose_cvt(
    const TS* __restrict__ src, int ldsrc, ll sS1, ll sS2,
    ushort* __restrict__ dst, int lddst, ll sD1, ll sD2, int Z2)
{
    __shared__ ushort tile[64][68];
    const int z1 = blockIdx.z / Z2, z2 = blockIdx.z % Z2;
    src += z1 * sS1 + z2 * sS2;
    dst += z1 * sD1 + z2 * sD2;
    const int r0 = blockIdx.y * 64, c0 = blockIdx.x * 64;
    const int t = threadIdx.x;
    #pragma unroll
    for (int j = 0; j < 4; j++) {
        int idx = t + 256 * j;
        int r = idx >> 4, c = (idx & 15) * 4;
        if constexpr (sizeof(TS) == 4) {
            float4 v = *reinterpret_cast<const float4*>(src + (ll)(r0 + r) * ldsrc + c0 + c);
            tile[r][c]     = f2b(v.x);
            tile[r][c + 1] = f2b(v.y);
            tile[r][c + 2] = f2b(v.z);
            tile[r][c + 3] = f2b(v.w);
        } else {
            *reinterpret_cast<us4*>(&tile[r][c]) =
                *reinterpret_cast<const us4*>(src + (ll)(r0 + r) * ldsrc + c0 + c);
        }
    }
    __syncthreads();
    #pragma unroll
    for (int j = 0; j < 4; j++) {
        int idx = t + 256 * j;
        int rr = idx >> 4, cc = (idx & 15) * 4;   // dst row within tile, dst col base
        us4 w;
        w.x = tile[cc][rr]; w.y = tile[cc + 1][rr];
        w.z = tile[cc + 2][rr]; w.w = tile[cc + 3][rr];
        *reinterpret_cast<us4*>(&dst[(ll)(c0 + rr) * lddst + r0 + cc]) = w;
    }
}

// ---------------------------------------------------------------------------
// MFMA bf16 GEMM (m97 structure): C[M,N] = act(alpha * A@B^T + bias)
//   A: [M][K] bf16 K-contig (lda), B: [N][K] bf16 K-contig (ldb).
//   BK=32; LDS unpadded [rows][32] (64 B rows), staged via global_load_lds x16B.
//   WR x WC waves; BM = WR*MI*16, BN = WC*NI*16.  Batched via z = z1*Z2+z2.
// ---------------------------------------------------------------------------
template<int WR, int WC, int MI, int NI, int ACT, typename TC>
__global__ __launch_bounds__(256) void gemm_bf16(
    const ushort* __restrict__ A, int lda, ll sA1, ll sA2,
    const ushort* __restrict__ B, int ldb, ll sB1, ll sB2,
    const float* __restrict__ bias, ll sb1, ll sb2,
    TC* __restrict__ C, int ldc, ll sC1, ll sC2,
    int K, int Z2, float alpha)
{
    constexpr int BM = WR * MI * 16;
    constexpr int BN = WC * NI * 16;
    __shared__ alignas(16) ushort As[BM * 32];
    __shared__ alignas(16) ushort Bs[BN * 32];

    const int z1 = blockIdx.z / Z2, z2 = blockIdx.z % Z2;
    A += z1 * sA1 + z2 * sA2;
    B += z1 * sB1 + z2 * sB2;
    C += z1 * sC1 + z2 * sC2;

    const int t = threadIdx.x;
    const int m0 = blockIdx.y * BM, n0 = blockIdx.x * BN;
    const int lane = t & 63, wave = t >> 6;
    const int quad = lane >> 4, l16 = lane & 15;
    const int wm = wave / WC, wn = wave % WC;

    f32x4 acc[MI][NI] = {};

    for (int k0 = 0; k0 < K; k0 += 32) {
        // stage A tile: BM rows x 32 k, 16B per lane, linear LDS
        #pragma unroll
        for (int i = 0; i < BM / 64; i++) {
            int seg = i * 256 + t;
            int row = seg >> 2, ke = (seg & 3) * 8;
            gload16(A + (ll)(m0 + row) * lda + (k0 + ke), &As[seg * 8]);
        }
        #pragma unroll
        for (int i = 0; i < BN / 64; i++) {
            int seg = i * 256 + t;
            int row = seg >> 2, ke = (seg & 3) * 8;
            gload16(B + (ll)(n0 + row) * ldb + (k0 + ke), &Bs[seg * 8]);
        }
        __syncthreads();   // compiler drains vmcnt(0) before barrier

        short8 a[MI], b[NI];
        #pragma unroll
        for (int mi = 0; mi < MI; mi++)
            a[mi] = *reinterpret_cast<const short8*>(
                &As[(wm * MI * 16 + mi * 16 + l16) * 32 + quad * 8]);
        #pragma unroll
        for (int ni = 0; ni < NI; ni++)
            b[ni] = *reinterpret_cast<const short8*>(
                &Bs[(wn * NI * 16 + ni * 16 + l16) * 32 + quad * 8]);
        #pragma unroll
        for (int mi = 0; mi < MI; mi++)
            #pragma unroll
            for (int ni = 0; ni < NI; ni++)
                acc[mi][ni] = __builtin_amdgcn_mfma_f32_16x16x32_bf16(
                    a[mi], b[ni], acc[mi][ni], 0, 0, 0);
        __syncthreads();
    }

    const float* bz = bias ? (bias + z1 * sb1 + z2 * sb2) : nullptr;
    #pragma unroll
    for (int mi = 0; mi < MI; mi++) {
        #pragma unroll
        for (int ni = 0; ni < NI; ni++) {
            const int row = m0 + wm * MI * 16 + mi * 16 + quad * 4;
            const int col = n0 + wn * NI * 16 + ni * 16 + l16;
            const float bv = bz ? bz[col] : 0.f;
            #pragma unroll
            for (int r = 0; r < 4; r++) {
                float v = alpha * acc[mi][ni][r] + bv;
                if (ACT) v = gelu_f(v);
                if constexpr (sizeof(TC) == 2)
                    C[(ll)(row + r) * ldc + col] = f2b(v);
                else
                    C[(ll)(row + r) * ldc + col] = v;
            }
        }
    }
}

// ---------------------------------------------------------------------------
// Attention softmax over m, v2 (vectorized).  p: bf16 (b,h,n,m), normalized
// in place (for AV) and written as fp32 attn_out in (b,n,m,h) layout.
// grid (SEQ, BATCH); 4 waves; 4 head-groups; lane owns 16 contiguous m.
// LDS 16 KiB -> 8 blocks/CU.
// ---------------------------------------------------------------------------
__global__ __launch_bounds__(256) void attn_softmax(
    ushort* __restrict__ p, float* __restrict__ attn_out)
{
    __shared__ float tile[4][1024];
    const int n = blockIdx.x, b = blockIdx.y;
    const int t = threadIdx.x;
    const int lane = t & 63, w = t >> 6;
    float* outp = attn_out + ((ll)b * SEQ + n) * SEQ * HEADS;
    #pragma unroll 1
    for (int g = 0; g < 4; g++) {
        const int h = g * 4 + w;
        ushort* row = p + ((ll)(b * HEADS + h) * SEQ + n) * SEQ + lane * 16;
        uint4 r0 = reinterpret_cast<const uint4*>(row)[0];
        uint4 r1 = reinterpret_cast<const uint4*>(row)[1];
        uint rr[8] = {r0.x, r0.y, r0.z, r0.w, r1.x, r1.y, r1.z, r1.w};
        float v[16];
        float m = -3.0e38f;
        #pragma unroll
        for (int j = 0; j < 8; j++) {
            v[2 * j]     = b2f((ushort)(rr[j] & 0xFFFFu));
            v[2 * j + 1] = b2f((ushort)(rr[j] >> 16));
            m = fmaxf(m, fmaxf(v[2 * j], v[2 * j + 1]));
        }
        #pragma unroll
        for (int o = 32; o; o >>= 1) m = fmaxf(m, __shfl_xor(m, o));
        float s = 0.f;
        #pragma unroll
        for (int j = 0; j < 16; j++) { v[j] = __expf(v[j] - m); s += v[j]; }
        #pragma unroll
        for (int o = 32; o; o >>= 1) s += __shfl_xor(s, o);
        const float inv = 1.f / s;
        #pragma unroll
        for (int j = 0; j < 16; j++) v[j] *= inv;
        // write back normalized bf16 p (for AV GEMM)
        uint pw[8];
        #pragma unroll
        for (int j = 0; j < 8; j++) pw[j] = pk(v[2 * j], v[2 * j + 1]);
        uint4 w0, w1;
        w0.x = pw[0]; w0.y = pw[1]; w0.z = pw[2]; w0.w = pw[3];
        w1.x = pw[4]; w1.y = pw[5]; w1.z = pw[6]; w1.w = pw[7];
        reinterpret_cast<uint4*>(row)[0] = w0;
        reinterpret_cast<uint4*>(row)[1] = w1;
        // LDS transpose bounce (XOR-swizzled to dodge bank conflicts on read)
        const int sw = (h & 7) << 2;
        #pragma unroll
        for (int jj = 0; jj < 4; jj++) {
            float4 f4;
            f4.x = v[4 * jj]; f4.y = v[4 * jj + 1];
            f4.z = v[4 * jj + 2]; f4.w = v[4 * jj + 3];
            *reinterpret_cast<float4*>(&tile[w][(lane * 16 + 4 * jj) ^ sw]) = f4;
        }
        __syncthreads();
        const int c0 = ((4 * g + 0) & 7) << 2, c1 = ((4 * g + 1) & 7) << 2;
        const int c2 = ((4 * g + 2) & 7) << 2, c3 = ((4 * g + 3) & 7) << 2;
        #pragma unroll
        for (int jj = 0; jj < 4; jj++) {
            int mm = t + 256 * jj;
            float4 o4;
            o4.x = tile[0][mm ^ c0];
            o4.y = tile[1][mm ^ c1];
            o4.z = tile[2][mm ^ c2];
            o4.w = tile[3][mm ^ c3];
            *reinterpret_cast<float4*>(&outp[(ll)mm * HEADS + 4 * g]) = o4;
        }
        __syncthreads();
    }
}

// ---------------------------------------------------------------------------
// LayerNorm (vectorized): out_row = LN(a_row + coef*b_row) * g + beta
// Optionally also writes bf16 copy.  1 block per row; thread owns 4 elems.
// ---------------------------------------------------------------------------
__global__ __launch_bounds__(256) void ln_kernel(
    const float* __restrict__ a, const float* __restrict__ b, float coef,
    const float* __restrict__ g, const float* __restrict__ beta,
    float* __restrict__ out, ushort* __restrict__ out_bf)
{
    const int row = blockIdx.x;
    const int t = threadIdx.x;
    float4 av = reinterpret_cast<const float4*>(a + (ll)row * DIM)[t];
    float4 bv = reinterpret_cast<const float4*>(b + (ll)row * DIM)[t];
    float4 v;
    v.x = av.x + coef * bv.x; v.y = av.y + coef * bv.y;
    v.z = av.z + coef * bv.z; v.w = av.w + coef * bv.w;
    float s1 = v.x + v.y + v.z + v.w;
    float s2 = v.x * v.x + v.y * v.y + v.z * v.z + v.w * v.w;
    __shared__ float red[8];
    #pragma unroll
    for (int o = 32; o; o >>= 1) { s1 += __shfl_xor(s1, o); s2 += __shfl_xor(s2, o); }
    int w = t >> 6;
    if ((t & 63) == 0) { red[w] = s1; red[4 + w] = s2; }
    __syncthreads();
    s1 = red[0] + red[1] + red[2] + red[3];
    s2 = red[4] + red[5] + red[6] + red[7];
    float mu = s1 * (1.f / DIM);
    float var = s2 * (1.f / DIM) - mu * mu;
    float rs = rsqrtf(var + LNEPS);
    float4 gv = reinterpret_cast<const float4*>(g)[t];
    float4 be = reinterpret_cast<const float4*>(beta)[t];
    float4 o;
    o.x = (v.x - mu) * rs * gv.x + be.x;
    o.y = (v.y - mu) * rs * gv.y + be.y;
    o.z = (v.z - mu) * rs * gv.z + be.z;
    o.w = (v.w - mu) * rs * gv.w + be.w;
    reinterpret_cast<float4*>(out + (ll)row * DIM)[t] = o;
    if (out_bf) {
        us4 hv;
        hv.x = f2b(o.x); hv.y = f2b(o.y); hv.z = f2b(o.z); hv.w = f2b(o.w);
        reinterpret_cast<us4*>(out_bf + (ll)row * DIM)[t] = hv;
    }
}

// ---------------------------------------------------------------------------
// dispatch = softmax over n of logits (b,n,es), written TRANSPOSED as
// dispT[b][es][n] in bf16 (row-major k=n contiguous -> standard GEMM A).
// ---------------------------------------------------------------------------
__global__ __launch_bounds__(256) void col_softmax(
    const float* __restrict__ logits, ushort* __restrict__ dispT)
{
    const int b = blockIdx.x, cc = blockIdx.y;
    const int cl = threadIdx.x & 63;
    const int c = cc * 64 + cl;
    const int rg = threadIdx.x >> 6;
    const float* L = logits + (ll)b * SEQ * ES + c;
    ushort* DT = dispT + (ll)b * ES * SEQ + (ll)c * SEQ;
    __shared__ float red[4][64];
    float m = -3.0e38f;
    for (int n = rg; n < SEQ; n += 4) m = fmaxf(m, L[(ll)n * ES]);
    red[rg][cl] = m;
    __syncthreads();
    m = fmaxf(fmaxf(red[0][cl], red[1][cl]), fmaxf(red[2][cl], red[3][cl]));
    __syncthreads();
    float s = 0.f;
    for (int n = rg; n < SEQ; n += 4) s += __expf(L[(ll)n * ES] - m);
    red[rg][cl] = s;
    __syncthreads();
    s = red[0][cl] + red[1][cl] + red[2][cl] + red[3][cl];
    float inv = 1.f / s;
    for (int n = rg; n < SEQ; n += 4)
        DT[n] = f2b(__expf(L[(ll)n * ES] - m) * inv);
}

// combine = softmax over es (rows of 1024), bf16 out
__global__ __launch_bounds__(256) void row_softmax(
    const float* __restrict__ logits, ushort* __restrict__ comb)
{
    const int row = blockIdx.x;
    const float* L = logits + (ll)row * ES;
    ushort* O = comb + (ll)row * ES;
    float v[4];
    float m = -3.0e38f;
    #pragma unroll
    for (int j = 0; j < 4; j++) { v[j] = L[threadIdx.x + 256 * j]; m = fmaxf(m, v[j]); }
    __shared__ float red[8];
    #pragma unroll
    for (int o = 32; o; o >>= 1) m = fmaxf(m, __shfl_xor(m, o));
    int w = threadIdx.x >> 6;
    if ((threadIdx.x & 63) == 0) red[w] = m;
    __syncthreads();
    m = fmaxf(fmaxf(red[0], red[1]), fmaxf(red[2], red[3]));
    __syncthreads();
    float s = 0.f;
    #pragma unroll
    for (int j = 0; j < 4; j++) { v[j] = __expf(v[j] - m); s += v[j]; }
    #pragma unroll
    for (int o = 32; o; o >>= 1) s += __shfl_xor(s, o);
    if ((threadIdx.x & 63) == 0) red[4 + w] = s;
    __syncthreads();
    s = red[4] + red[5] + red[6] + red[7];
    float inv = 1.f / s;
    #pragma unroll
    for (int j = 0; j < 4; j++) O[threadIdx.x + 256 * j] = f2b(v[j] * inv);
}

// ---------------------------------------------------------------------------
extern "C" void kernel_launch(void* const* d_in, const int* in_sizes, int n_in,
                              void* d_out, int out_size, void* d_ws, size_t ws_size,
                              hipStream_t stream)
{
    const float* x   = (const float*)d_in[0];
    const float* Wq  = (const float*)d_in[1];
    const float* bq  = (const float*)d_in[2];
    const float* Wkv = (const float*)d_in[3];
    const float* bkv = (const float*)d_in[4];
    const float* Wp  = (const float*)d_in[5];
    const float* bp  = (const float*)d_in[6];
    const float* g1  = (const float*)d_in[7];
    const float* b1  = (const float*)d_in[8];
    const float* phi = (const float*)d_in[9];
    const float* We1 = (const float*)d_in[10];
    const float* be1 = (const float*)d_in[11];
    const float* We2 = (const float*)d_in[12];
    const float* be2 = (const float*)d_in[13];
    const float* g2  = (const float*)d_in[14];
    const float* b2  = (const float*)d_in[15];

    float* out_y    = (float*)d_out;
    float* out_attn = out_y + (ll)BATCH * SEQ * DIM;

    // Workspace layout (float offsets, M1 = 1M floats).  Peak ~46.5M fl = 186 MB.
    // Phase-dead aliasing:
    //   moe [0,4M)        <- x_bf/WqkvT/WpT    (dead after qkv / Wp GEMMs)
    //   We1T [4.5,8.5M)   <- qkv_bf            (dead after scores+vT)
    //   We2T [8.5,12.5M)  <- qkv_bf tail + vT  (dead after AV)
    //   po   [12.5,16.5M) <- p_bf head         (dead after AV)
    //   x1..ymoe          <- rest of p_bf dead zone
    //   ymoeT [44.5M)     <- ao_bf             (dead after Wp GEMM)
    const ll M1 = 1024 * 1024;
    float*  ws     = (float*)d_ws;
    ushort* x_bf   = (ushort*)(ws);                 // [0, 2M)
    ushort* WqkvT  = (ushort*)(ws + 2 * M1);        // [2, 3.5M)   3072x1024 bf16
    ushort* WpT    = (ushort*)(ws + 7 * M1 / 2);    // [3.5, 4M)
    ushort* phiT   = (ushort*)(ws + 4 * M1);        // [4, 4.5M)
    ushort* qkv_bf = (ushort*)(ws + 9 * M1 / 2);    // [4.5, 10.5M) 4096x3072 bf16
    ushort* vT     = (ushort*)(ws + 21 * M1 / 2);   // [10.5, 12.5M)
    ushort* p_bf   = (ushort*)(ws + 25 * M1 / 2);   // [12.5, 44.5M)
    float*  po     = ws + 25 * M1 / 2;              //   (after AV)
    ushort* ao_bf  = (ushort*)(ws + 89 * M1 / 2);   // [44.5, 46.5M)
    ushort* ymoeT  = (ushort*)(ws + 89 * M1 / 2);   //   (phase 2 alias)
    float*  x1     = ws + 33 * M1 / 2;              // [16.5, 20.5M)
    ushort* x1_bf  = (ushort*)(ws + 41 * M1 / 2);   // [20.5, 22.5M)
    ushort* x1T    = (ushort*)(ws + 45 * M1 / 2);   // [22.5, 24.5M)
    float*  logit  = ws + 49 * M1 / 2;              // [24.5, 28.5M)
    ushort* dispT  = (ushort*)(ws + 57 * M1 / 2);   // [28.5, 30.5M)
    ushort* comb   = (ushort*)(ws + 61 * M1 / 2);   // [30.5, 32.5M)
    ushort* slots  = (ushort*)(ws + 65 * M1 / 2);   // [32.5, 34.5M)
    ushort* hmid   = (ushort*)(ws + 69 * M1 / 2);   // [34.5, 42.5M)
    ushort* ymoe   = (ushort*)(ws + 85 * M1 / 2);   // [42.5, 44.5M)
    ushort* We1T   = (ushort*)(ws + 9 * M1 / 2);    // [4.5, 8.5M)  phase 2
    ushort* We2T   = (ushort*)(ws + 17 * M1 / 2);   // [8.5, 12.5M) phase 2
    float*  bqkv   = ws + 93 * M1 / 2;              // [46.5M, +3072)
    float*  moe    = ws;                            // [0, 4M) phase 2

    dim3 blk(256);

    // 0: bf16 conversions / weight transposes for the attention phase
    cvt_bf16<<<dim3(2048), blk, 0, stream>>>(x, x_bf);
    transpose_cvt<float><<<dim3(16, 16, 1), blk, 0, stream>>>(
        Wq, DIM, 0, 0, WqkvT, DIM, 0, 0, 1);
    transpose_cvt<float><<<dim3(32, 16, 1), blk, 0, stream>>>(
        Wkv, 2 * DIM, 0, 0, WqkvT + (ll)DIM * DIM, DIM, 0, 0, 1);
    transpose_cvt<float><<<dim3(16, 16, 1), blk, 0, stream>>>(
        Wp, DIM, 0, 0, WpT, DIM, 0, 0, 1);
    transpose_cvt<float><<<dim3(16, 16, 1), blk, 0, stream>>>(
        phi, ES, 0, 0, phiT, DIM, 0, 0, 1);
    concat_bias<<<dim3(12), blk, 0, stream>>>(bq, bkv, bqkv);

    // 1: fused QKV projection (N=3072, bf16 out)
    gemm_bf16<2,2,4,4,0,ushort><<<dim3(24, 32, 1), blk, 0, stream>>>(
        x_bf, DIM, 0, 0, WqkvT, DIM, 0, 0, bqkv, 0, 0,
        qkv_bf, 3 * DIM, 0, 0, DIM, 1, 1.f);

    // 2: vT[b,h][d][m] <- v slice of qkv (for K-contiguous AV B operand)
    transpose_cvt<ushort><<<dim3(1, 16, BATCH * HEADS), blk, 0, stream>>>(
        qkv_bf + 2 * DIM, 3 * DIM, (ll)SEQ * 3 * DIM, HD,
        vT, SEQ, (ll)HEADS * HD * SEQ, (ll)HD * SEQ, HEADS);

    // 3: scores p[b,h,n,m] = 0.125 * q_bh @ k_bh^T  (bf16 out)
    gemm_bf16<2,2,4,4,0,ushort><<<dim3(8, 8, BATCH * HEADS), blk, 0, stream>>>(
        qkv_bf, 3 * DIM, (ll)SEQ * 3 * DIM, HD,
        qkv_bf + DIM, 3 * DIM, (ll)SEQ * 3 * DIM, HD,
        nullptr, 0, 0,
        p_bf, SEQ, (ll)HEADS * SEQ * SEQ, (ll)SEQ * SEQ,
        HD, HEADS, 0.125f);

    // 4: softmax over m (in-place bf16) + fp32 bnmh attn output
    attn_softmax<<<dim3(SEQ, BATCH), blk, 0, stream>>>(p_bf, out_attn);

    // 5: ao[b,n,h*64+d] = p_bh @ vT_bh^T   (BM=128, BN=64; bf16 out)
    gemm_bf16<4,1,2,4,0,ushort><<<dim3(1, 8, BATCH * HEADS), blk, 0, stream>>>(
        p_bf, SEQ, (ll)HEADS * SEQ * SEQ, (ll)SEQ * SEQ,
        vT, SEQ, (ll)HEADS * HD * SEQ, (ll)HD * SEQ,
        nullptr, 0, 0,
        ao_bf, DIM, (ll)SEQ * DIM, HD,
        SEQ, HEADS, 1.f);

    // 6: output projection (fp32 out for LN residual)
    gemm_bf16<2,2,4,4,0,float><<<dim3(8, 32, 1), blk, 0, stream>>>(
        ao_bf, DIM, 0, 0, WpT, DIM, 0, 0, bp, 0, 0,
        po, DIM, 0, 0, DIM, 1, 1.f);
    // 7: x1 = LN(po + x)  (fp32 + bf16 copies)
    ln_kernel<<<dim3(NTOK), blk, 0, stream>>>(po, x, 1.0f, g1, b1, x1, x1_bf);

    // 7b: MoE weight transposes (into attn-dead regions) + x1T
    transpose_cvt<float><<<dim3(64, 16, 2), blk, 0, stream>>>(
        We1, HID, 0, (ll)DIM * HID, We1T, DIM, 0, (ll)HID * DIM, 2);
    transpose_cvt<float><<<dim3(16, 64, 2), blk, 0, stream>>>(
        We2, DIM, 0, (ll)HID * DIM, We2T, HID, 0, (ll)DIM * HID, 2);
    transpose_cvt<ushort><<<dim3(16, 16, BATCH), blk, 0, stream>>>(
        x1_bf, DIM, (ll)SEQ * DIM, 0, x1T, SEQ, (ll)DIM * SEQ, 0, 1);

    // 8: moe logits = x1 @ phi (fp32 out for softmaxes)
    gemm_bf16<2,2,4,4,0,float><<<dim3(8, 32, 1), blk, 0, stream>>>(
        x1_bf, DIM, 0, 0, phiT, DIM, 0, 0, nullptr, 0, 0,
        logit, ES, 0, 0, DIM, 1, 1.f);
    // 9-10: dispatch (transposed bf16) and combine (bf16) softmaxes
    col_softmax<<<dim3(BATCH, 16), blk, 0, stream>>>(logit, dispT);
    row_softmax<<<dim3(NTOK), blk, 0, stream>>>(logit, comb);

    // 11: slots[b] = dispT[b] @ x1T[b]^T   (ES x DIM, K=SEQ)
    gemm_bf16<2,2,4,4,0,ushort><<<dim3(8, 8, BATCH), blk, 0, stream>>>(
        dispT, SEQ, (ll)ES * SEQ, 0,
        x1T, SEQ, (ll)DIM * SEQ, 0,
        nullptr, 0, 0,
        slots, DIM, (ll)ES * DIM, 0,
        SEQ, 1, 1.f);

    // 12: hmid = gelu(slots @ We1 + be1), z = b*NEXP+e
    gemm_bf16<2,2,4,4,1,ushort><<<dim3(32, 4, BATCH * NEXP), blk, 0, stream>>>(
        slots, DIM, (ll)ES * DIM, (ll)NSLOT * DIM,
        We1T, DIM, 0, (ll)HID * DIM,
        be1, 0, HID,
        hmid, HID, (ll)ES * HID, (ll)NSLOT * HID,
        DIM, NEXP, 1.f);

    // 13: ymoe = hmid @ We2 + be2
    gemm_bf16<2,2,4,4,0,ushort><<<dim3(8, 4, BATCH * NEXP), blk, 0, stream>>>(
        hmid, HID, (ll)ES * HID, (ll)NSLOT * HID,
        We2T, HID, 0, (ll)DIM * HID,
        be2, 0, DIM,
        ymoe, DIM, (ll)ES * DIM, (ll)NSLOT * DIM,
        HID, NEXP, 1.f);

    // 13b: ymoeT[b][d][es] <- ymoe
    transpose_cvt<ushort><<<dim3(16, 16, BATCH), blk, 0, stream>>>(
        ymoe, DIM, (ll)ES * DIM, 0, ymoeT, ES, (ll)DIM * ES, 0, 1);

    // 14: moe[b] = comb[b] @ ymoeT[b]^T
    gemm_bf16<2,2,4,4,0,float><<<dim3(8, 8, BATCH), blk, 0, stream>>>(
        comb, ES, (ll)SEQ * ES, 0,
        ymoeT, ES, (ll)DIM * ES, 0,
        nullptr, 0, 0,
        moe, DIM, (ll)SEQ * DIM, 0,
        ES, 1, 1.f);

    // 15: y = LN(moe + 2*x1)
    ln_kernel<<<dim3(NTOK), blk, 0, stream>>>(moe, x1, 2.0f, g2, b2, out_y, nullptr);
}

// Round 3
// 1064.747 us; speedup vs baseline: 1.1181x; 1.1181x over previous
//
#include <hip/hip_runtime.h>
#include <math.h>

// Problem constants
#define BATCH 4
#define SEQ   1024
#define DIM   1024
#define HEADS 16
#define HD    64
#define NEXP  2
#define NSLOT 512
#define ES    1024       // NEXP*NSLOT
#define HID   4096
#define LNEPS 1e-5f
#define NTOK  (BATCH*SEQ)

typedef long long ll;
typedef unsigned short ushort;
typedef unsigned int uint;
typedef __attribute__((ext_vector_type(8))) short short8;   // 8 bf16 (4 VGPRs)
typedef __attribute__((ext_vector_type(4))) float f32x4;    // MFMA accum
typedef __attribute__((ext_vector_type(4))) unsigned short us4;

__device__ __forceinline__ ushort f2b(float f) {            // fp32 -> bf16 RNE
    uint u = __builtin_bit_cast(uint, f);
    u += 0x7FFFu + ((u >> 16) & 1u);
    return (ushort)(u >> 16);
}
__device__ __forceinline__ float b2f(ushort h) {
    uint u = ((uint)h) << 16;
    return __builtin_bit_cast(float, u);
}
__device__ __forceinline__ uint pk(float a, float b) {
    return (uint)f2b(a) | ((uint)f2b(b) << 16);
}
__device__ __forceinline__ float gelu_f(float v) {
    float x3 = v * v * v;
    return 0.5f * v * (1.f + tanhf(0.7978845608028654f * (v + 0.044715f * x3)));
}

// async global->LDS, 16B per lane.  LDS dest must be wave-uniform base + lane*16.
__device__ __forceinline__ void gload16(const ushort* g, ushort* l) {
    __builtin_amdgcn_global_load_lds(
        (const __attribute__((address_space(1))) unsigned int*)(const void*)g,
        (__attribute__((address_space(3))) unsigned int*)(void*)l,
        16, 0, 0);
}

// ---------------------------------------------------------------------------
// fp32 -> bf16 elementwise convert, 8 elems/thread (x: 4M elems, grid 2048)
// ---------------------------------------------------------------------------
__global__ __launch_bounds__(256) void cvt_bf16(
    const float* __restrict__ src, ushort* __restrict__ dst)
{
    int i = blockIdx.x * 256 + threadIdx.x;
    const float4* s = reinterpret_cast<const float4*>(src) + (ll)i * 2;
    float4 a = s[0], b = s[1];
    uint4 w;
    w.x = pk(a.x, a.y); w.y = pk(a.z, a.w);
    w.z = pk(b.x, b.y); w.w = pk(b.z, b.w);
    reinterpret_cast<uint4*>(dst)[i] = w;
}

// bias concat: o[0..1023] = a, o[1024..3071] = b   (grid 12)
__global__ __launch_bounds__(256) void concat_bias(
    const float* __restrict__ a, const float* __restrict__ b,
    float* __restrict__ o)
{
    int i = blockIdx.x * 256 + threadIdx.x;
    o[i] = (i < DIM) ? a[i] : b[i - DIM];
}

// ---------------------------------------------------------------------------
// Tiled transpose(+convert): dst[c][r] = bf16(src[r][c]).  64x64 tiles.
// grid (ncol/64, nrow/64, Z); z = z1*Z2+z2 with per-operand stride pairs.
// ---------------------------------------------------------------------------
template<typename TS>
__global__ __launch_bounds__(256) void transpose_cvt(
    const TS* __restrict__ src, int ldsrc, ll sS1, ll sS2,
    ushort* __restrict__ dst, int lddst, ll sD1, ll sD2, int Z2)
{
    __shared__ ushort tile[64][68];
    const int z1 = blockIdx.z / Z2, z2 = blockIdx.z % Z2;
    src += z1 * sS1 + z2 * sS2;
    dst += z1 * sD1 + z2 * sD2;
    const int r0 = blockIdx.y * 64, c0 = blockIdx.x * 64;
    const int t = threadIdx.x;
    #pragma unroll
    for (int j = 0; j < 4; j++) {
        int idx = t + 256 * j;
        int r = idx >> 4, c = (idx & 15) * 4;
        if constexpr (sizeof(TS) == 4) {
            float4 v = *reinterpret_cast<const float4*>(src + (ll)(r0 + r) * ldsrc + c0 + c);
            tile[r][c]     = f2b(v.x);
            tile[r][c + 1] = f2b(v.y);
            tile[r][c + 2] = f2b(v.z);
            tile[r][c + 3] = f2b(v.w);
        } else {
            *reinterpret_cast<us4*>(&tile[r][c]) =
                *reinterpret_cast<const us4*>(src + (ll)(r0 + r) * ldsrc + c0 + c);
        }
    }
    __syncthreads();
    #pragma unroll
    for (int j = 0; j < 4; j++) {
        int idx = t + 256 * j;
        int rr = idx >> 4, cc = (idx & 15) * 4;   // dst row within tile, dst col base
        us4 w;
        w.x = tile[cc][rr]; w.y = tile[cc + 1][rr];
        w.z = tile[cc + 2][rr]; w.w = tile[cc + 3][rr];
        *reinterpret_cast<us4*>(&dst[(ll)(c0 + rr) * lddst + r0 + cc]) = w;
    }
}

// ---------------------------------------------------------------------------
// MFMA bf16 GEMM (m97 structure): C[M,N] = act(alpha * A@B^T + bias)
//   A: [M][K] bf16 K-contig (lda), B: [N][K] bf16 K-contig (ldb).
//   BK=32; LDS unpadded [rows][32] (64 B rows), staged via global_load_lds x16B.
//   WR x WC waves; BM = WR*MI*16, BN = WC*NI*16.  Batched via z = z1*Z2+z2.
// ---------------------------------------------------------------------------
template<int WR, int WC, int MI, int NI, int ACT, typename TC>
__global__ __launch_bounds__(256) void gemm_bf16(
    const ushort* __restrict__ A, int lda, ll sA1, ll sA2,
    const ushort* __restrict__ B, int ldb, ll sB1, ll sB2,
    const float* __restrict__ bias, ll sb1, ll sb2,
    TC* __restrict__ C, int ldc, ll sC1, ll sC2,
    int K, int Z2, float alpha)
{
    constexpr int BM = WR * MI * 16;
    constexpr int BN = WC * NI * 16;
    __shared__ alignas(16) ushort As[BM * 32];
    __shared__ alignas(16) ushort Bs[BN * 32];

    const int z1 = blockIdx.z / Z2, z2 = blockIdx.z % Z2;
    A += z1 * sA1 + z2 * sA2;
    B += z1 * sB1 + z2 * sB2;
    C += z1 * sC1 + z2 * sC2;

    const int t = threadIdx.x;
    const int m0 = blockIdx.y * BM, n0 = blockIdx.x * BN;
    const int lane = t & 63, wave = t >> 6;
    const int quad = lane >> 4, l16 = lane & 15;
    const int wm = wave / WC, wn = wave % WC;

    f32x4 acc[MI][NI] = {};

    for (int k0 = 0; k0 < K; k0 += 32) {
        // stage A tile: BM rows x 32 k, 16B per lane, linear LDS
        #pragma unroll
        for (int i = 0; i < BM / 64; i++) {
            int seg = i * 256 + t;
            int row = seg >> 2, ke = (seg & 3) * 8;
            gload16(A + (ll)(m0 + row) * lda + (k0 + ke), &As[seg * 8]);
        }
        #pragma unroll
        for (int i = 0; i < BN / 64; i++) {
            int seg = i * 256 + t;
            int row = seg >> 2, ke = (seg & 3) * 8;
            gload16(B + (ll)(n0 + row) * ldb + (k0 + ke), &Bs[seg * 8]);
        }
        __syncthreads();   // compiler drains vmcnt(0) before barrier

        short8 a[MI], b[NI];
        #pragma unroll
        for (int mi = 0; mi < MI; mi++)
            a[mi] = *reinterpret_cast<const short8*>(
                &As[(wm * MI * 16 + mi * 16 + l16) * 32 + quad * 8]);
        #pragma unroll
        for (int ni = 0; ni < NI; ni++)
            b[ni] = *reinterpret_cast<const short8*>(
                &Bs[(wn * NI * 16 + ni * 16 + l16) * 32 + quad * 8]);
        #pragma unroll
        for (int mi = 0; mi < MI; mi++)
            #pragma unroll
            for (int ni = 0; ni < NI; ni++)
                acc[mi][ni] = __builtin_amdgcn_mfma_f32_16x16x32_bf16(
                    a[mi], b[ni], acc[mi][ni], 0, 0, 0);
        __syncthreads();
    }

    const float* bz = bias ? (bias + z1 * sb1 + z2 * sb2) : nullptr;
    #pragma unroll
    for (int mi = 0; mi < MI; mi++) {
        #pragma unroll
        for (int ni = 0; ni < NI; ni++) {
            const int row = m0 + wm * MI * 16 + mi * 16 + quad * 4;
            const int col = n0 + wn * NI * 16 + ni * 16 + l16;
            const float bv = bz ? bz[col] : 0.f;
            #pragma unroll
            for (int r = 0; r < 4; r++) {
                float v = alpha * acc[mi][ni][r] + bv;
                if (ACT) v = gelu_f(v);
                if constexpr (sizeof(TC) == 2)
                    C[(ll)(row + r) * ldc + col] = f2b(v);
                else
                    C[(ll)(row + r) * ldc + col] = v;
            }
        }
    }
}

// ---------------------------------------------------------------------------
// Attention softmax over m, v3.  p layout: (b, n, h, m) bf16 — all 16 head
// rows of one token are contiguous (32 KB).  Normalized in place (for AV) and
// written as fp32 attn_out (b, n, m, h) via a 64 KB LDS transpose tile.
// grid (SEQ, BATCH), 256 thr.  Per head row: lane owns 16 contiguous m.
// LDS tile row h holds m-granules (4 floats) at permuted position
// P(4l+jj) = jj*64 + l  ->  ds_write_b128 hits consecutive granules
// (conflict-free); read side ~4-way (cheap).  ONE barrier total; each thread
// stores full 64 B out lines (no partial-line amplification).
// ---------------------------------------------------------------------------
__global__ __launch_bounds__(256) void attn_softmax(
    ushort* __restrict__ p, float* __restrict__ attn_out)
{
    __shared__ float tile[16][1024];
    const int n = blockIdx.x, b = blockIdx.y;
    const int t = threadIdx.x;
    const int lane = t & 63, w = t >> 6;
    ushort* base = p + ((ll)(b * SEQ + n) * HEADS) * SEQ;
    #pragma unroll 1
    for (int g = 0; g < 4; g++) {
        const int h = g * 4 + w;
        ushort* row = base + (ll)h * SEQ + lane * 16;
        uint4 r0 = reinterpret_cast<const uint4*>(row)[0];
        uint4 r1 = reinterpret_cast<const uint4*>(row)[1];
        uint rr[8] = {r0.x, r0.y, r0.z, r0.w, r1.x, r1.y, r1.z, r1.w};
        float v[16];
        float m = -3.0e38f;
        #pragma unroll
        for (int j = 0; j < 8; j++) {
            v[2 * j]     = b2f((ushort)(rr[j] & 0xFFFFu));
            v[2 * j + 1] = b2f((ushort)(rr[j] >> 16));
            m = fmaxf(m, fmaxf(v[2 * j], v[2 * j + 1]));
        }
        #pragma unroll
        for (int o = 32; o; o >>= 1) m = fmaxf(m, __shfl_xor(m, o));
        float s = 0.f;
        #pragma unroll
        for (int j = 0; j < 16; j++) { v[j] = __expf(v[j] - m); s += v[j]; }
        #pragma unroll
        for (int o = 32; o; o >>= 1) s += __shfl_xor(s, o);
        const float inv = 1.f / s;
        #pragma unroll
        for (int j = 0; j < 16; j++) v[j] *= inv;
        // write back normalized bf16 p (for AV GEMM)
        uint pw[8];
        #pragma unroll
        for (int j = 0; j < 8; j++) pw[j] = pk(v[2 * j], v[2 * j + 1]);
        uint4 w0, w1;
        w0.x = pw[0]; w0.y = pw[1]; w0.z = pw[2]; w0.w = pw[3];
        w1.x = pw[4]; w1.y = pw[5]; w1.z = pw[6]; w1.w = pw[7];
        reinterpret_cast<uint4*>(row)[0] = w0;
        reinterpret_cast<uint4*>(row)[1] = w1;
        // LDS: granule gm = 4*lane+jj stored at position jj*64+lane
        // -> per-instr consecutive granules across lanes (conflict-free b128)
        #pragma unroll
        for (int jj = 0; jj < 4; jj++) {
            float4 f4;
            f4.x = v[4 * jj]; f4.y = v[4 * jj + 1];
            f4.z = v[4 * jj + 2]; f4.w = v[4 * jj + 3];
            *reinterpret_cast<float4*>(&tile[h][(jj * 64 + lane) * 4]) = f4;
        }
    }
    __syncthreads();
    // out[(b,n)][m][h]: thread t handles mm = t + 256*jj; reads 16 scalars
    // (position P(gm)=( gm&3)*64+(gm>>2), gm=mm>>2), writes one full 64B line.
    float* outp = attn_out + ((ll)b * SEQ + n) * SEQ * HEADS;
    #pragma unroll
    for (int jj = 0; jj < 4; jj++) {
        const int mm = t + 256 * jj;
        const int gm = mm >> 2;
        const int fi = ((gm & 3) * 64 + (gm >> 2)) * 4 + (mm & 3);
        float o16[16];
        #pragma unroll
        for (int h = 0; h < 16; h++) o16[h] = tile[h][fi];
        float4* dst = reinterpret_cast<float4*>(outp + (ll)mm * HEADS);
        #pragma unroll
        for (int q = 0; q < 4; q++) {
            float4 o4;
            o4.x = o16[4 * q]; o4.y = o16[4 * q + 1];
            o4.z = o16[4 * q + 2]; o4.w = o16[4 * q + 3];
            dst[q] = o4;
        }
    }
}

// ---------------------------------------------------------------------------
// LayerNorm (vectorized): out_row = LN(a_row + coef*b_row) * g + beta
// Optionally also writes bf16 copy.  1 block per row; thread owns 4 elems.
// ---------------------------------------------------------------------------
__global__ __launch_bounds__(256) void ln_kernel(
    const float* __restrict__ a, const float* __restrict__ b, float coef,
    const float* __restrict__ g, const float* __restrict__ beta,
    float* __restrict__ out, ushort* __restrict__ out_bf)
{
    const int row = blockIdx.x;
    const int t = threadIdx.x;
    float4 av = reinterpret_cast<const float4*>(a + (ll)row * DIM)[t];
    float4 bv = reinterpret_cast<const float4*>(b + (ll)row * DIM)[t];
    float4 v;
    v.x = av.x + coef * bv.x; v.y = av.y + coef * bv.y;
    v.z = av.z + coef * bv.z; v.w = av.w + coef * bv.w;
    float s1 = v.x + v.y + v.z + v.w;
    float s2 = v.x * v.x + v.y * v.y + v.z * v.z + v.w * v.w;
    __shared__ float red[8];
    #pragma unroll
    for (int o = 32; o; o >>= 1) { s1 += __shfl_xor(s1, o); s2 += __shfl_xor(s2, o); }
    int w = t >> 6;
    if ((t & 63) == 0) { red[w] = s1; red[4 + w] = s2; }
    __syncthreads();
    s1 = red[0] + red[1] + red[2] + red[3];
    s2 = red[4] + red[5] + red[6] + red[7];
    float mu = s1 * (1.f / DIM);
    float var = s2 * (1.f / DIM) - mu * mu;
    float rs = rsqrtf(var + LNEPS);
    float4 gv = reinterpret_cast<const float4*>(g)[t];
    float4 be = reinterpret_cast<const float4*>(beta)[t];
    float4 o;
    o.x = (v.x - mu) * rs * gv.x + be.x;
    o.y = (v.y - mu) * rs * gv.y + be.y;
    o.z = (v.z - mu) * rs * gv.z + be.z;
    o.w = (v.w - mu) * rs * gv.w + be.w;
    reinterpret_cast<float4*>(out + (ll)row * DIM)[t] = o;
    if (out_bf) {
        us4 hv;
        hv.x = f2b(o.x); hv.y = f2b(o.y); hv.z = f2b(o.z); hv.w = f2b(o.w);
        reinterpret_cast<us4*>(out_bf + (ll)row * DIM)[t] = hv;
    }
}

// ---------------------------------------------------------------------------
// dispatch = softmax over n of logits (b,n,es), written TRANSPOSED as
// dispT[b][es][n] in bf16 (row-major k=n contiguous -> standard GEMM A).
// ---------------------------------------------------------------------------
__global__ __launch_bounds__(256) void col_softmax(
    const float* __restrict__ logits, ushort* __restrict__ dispT)
{
    const int b = blockIdx.x, cc = blockIdx.y;
    const int cl = threadIdx.x & 63;
    const int c = cc * 64 + cl;
    const int rg = threadIdx.x >> 6;
    const float* L = logits + (ll)b * SEQ * ES + c;
    ushort* DT = dispT + (ll)b * ES * SEQ + (ll)c * SEQ;
    __shared__ float red[4][64];
    float m = -3.0e38f;
    for (int n = rg; n < SEQ; n += 4) m = fmaxf(m, L[(ll)n * ES]);
    red[rg][cl] = m;
    __syncthreads();
    m = fmaxf(fmaxf(red[0][cl], red[1][cl]), fmaxf(red[2][cl], red[3][cl]));
    __syncthreads();
    float s = 0.f;
    for (int n = rg; n < SEQ; n += 4) s += __expf(L[(ll)n * ES] - m);
    red[rg][cl] = s;
    __syncthreads();
    s = red[0][cl] + red[1][cl] + red[2][cl] + red[3][cl];
    float inv = 1.f / s;
    for (int n = rg; n < SEQ; n += 4)
        DT[n] = f2b(__expf(L[(ll)n * ES] - m) * inv);
}

// combine = softmax over es (rows of 1024), bf16 out
__global__ __launch_bounds__(256) void row_softmax(
    const float* __restrict__ logits, ushort* __restrict__ comb)
{
    const int row = blockIdx.x;
    const float* L = logits + (ll)row * ES;
    ushort* O = comb + (ll)row * ES;
    float v[4];
    float m = -3.0e38f;
    #pragma unroll
    for (int j = 0; j < 4; j++) { v[j] = L[threadIdx.x + 256 * j]; m = fmaxf(m, v[j]); }
    __shared__ float red[8];
    #pragma unroll
    for (int o = 32; o; o >>= 1) m = fmaxf(m, __shfl_xor(m, o));
    int w = threadIdx.x >> 6;
    if ((threadIdx.x & 63) == 0) red[w] = m;
    __syncthreads();
    m = fmaxf(fmaxf(red[0], red[1]), fmaxf(red[2], red[3]));
    __syncthreads();
    float s = 0.f;
    #pragma unroll
    for (int j = 0; j < 4; j++) { v[j] = __expf(v[j] - m); s += v[j]; }
    #pragma unroll
    for (int o = 32; o; o >>= 1) s += __shfl_xor(s, o);
    if ((threadIdx.x & 63) == 0) red[4 + w] = s;
    __syncthreads();
    s = red[4] + red[5] + red[6] + red[7];
    float inv = 1.f / s;
    #pragma unroll
    for (int j = 0; j < 4; j++) O[threadIdx.x + 256 * j] = f2b(v[j] * inv);
}

// ---------------------------------------------------------------------------
extern "C" void kernel_launch(void* const* d_in, const int* in_sizes, int n_in,
                              void* d_out, int out_size, void* d_ws, size_t ws_size,
                              hipStream_t stream)
{
    const float* x   = (const float*)d_in[0];
    const float* Wq  = (const float*)d_in[1];
    const float* bq  = (const float*)d_in[2];
    const float* Wkv = (const float*)d_in[3];
    const float* bkv = (const float*)d_in[4];
    const float* Wp  = (const float*)d_in[5];
    const float* bp  = (const float*)d_in[6];
    const float* g1  = (const float*)d_in[7];
    const float* b1  = (const float*)d_in[8];
    const float* phi = (const float*)d_in[9];
    const float* We1 = (const float*)d_in[10];
    const float* be1 = (const float*)d_in[11];
    const float* We2 = (const float*)d_in[12];
    const float* be2 = (const float*)d_in[13];
    const float* g2  = (const float*)d_in[14];
    const float* b2  = (const float*)d_in[15];

    float* out_y    = (float*)d_out;
    float* out_attn = out_y + (ll)BATCH * SEQ * DIM;

    // Workspace layout (float offsets, M1 = 1M floats).  Peak ~46.5M fl = 186 MB.
    const ll M1 = 1024 * 1024;
    float*  ws     = (float*)d_ws;
    ushort* x_bf   = (ushort*)(ws);                 // [0, 2M)
    ushort* WqkvT  = (ushort*)(ws + 2 * M1);        // [2, 3.5M)   3072x1024 bf16
    ushort* WpT    = (ushort*)(ws + 7 * M1 / 2);    // [3.5, 4M)
    ushort* phiT   = (ushort*)(ws + 4 * M1);        // [4, 4.5M)
    ushort* qkv_bf = (ushort*)(ws + 9 * M1 / 2);    // [4.5, 10.5M) 4096x3072 bf16
    ushort* vT     = (ushort*)(ws + 21 * M1 / 2);   // [10.5, 12.5M)
    ushort* p_bf   = (ushort*)(ws + 25 * M1 / 2);   // [12.5, 44.5M)
    float*  po     = ws + 25 * M1 / 2;              //   (after AV)
    ushort* ao_bf  = (ushort*)(ws + 89 * M1 / 2);   // [44.5, 46.5M)
    ushort* ymoeT  = (ushort*)(ws + 89 * M1 / 2);   //   (phase 2 alias)
    float*  x1     = ws + 33 * M1 / 2;              // [16.5, 20.5M)
    ushort* x1_bf  = (ushort*)(ws + 41 * M1 / 2);   // [20.5, 22.5M)
    ushort* x1T    = (ushort*)(ws + 45 * M1 / 2);   // [22.5, 24.5M)
    float*  logit  = ws + 49 * M1 / 2;              // [24.5, 28.5M)
    ushort* dispT  = (ushort*)(ws + 57 * M1 / 2);   // [28.5, 30.5M)
    ushort* comb   = (ushort*)(ws + 61 * M1 / 2);   // [30.5, 32.5M)
    ushort* slots  = (ushort*)(ws + 65 * M1 / 2);   // [32.5, 34.5M)
    ushort* hmid   = (ushort*)(ws + 69 * M1 / 2);   // [34.5, 42.5M)
    ushort* ymoe   = (ushort*)(ws + 85 * M1 / 2);   // [42.5, 44.5M)
    ushort* We1T   = (ushort*)(ws + 9 * M1 / 2);    // [4.5, 8.5M)  phase 2
    ushort* We2T   = (ushort*)(ws + 17 * M1 / 2);   // [8.5, 12.5M) phase 2
    float*  bqkv   = ws + 93 * M1 / 2;              // [46.5M, +3072)
    float*  moe    = ws;                            // [0, 4M) phase 2

    dim3 blk(256);

    // 0: bf16 conversions / weight transposes for the attention phase
    cvt_bf16<<<dim3(2048), blk, 0, stream>>>(x, x_bf);
    transpose_cvt<float><<<dim3(16, 16, 1), blk, 0, stream>>>(
        Wq, DIM, 0, 0, WqkvT, DIM, 0, 0, 1);
    transpose_cvt<float><<<dim3(32, 16, 1), blk, 0, stream>>>(
        Wkv, 2 * DIM, 0, 0, WqkvT + (ll)DIM * DIM, DIM, 0, 0, 1);
    transpose_cvt<float><<<dim3(16, 16, 1), blk, 0, stream>>>(
        Wp, DIM, 0, 0, WpT, DIM, 0, 0, 1);
    transpose_cvt<float><<<dim3(16, 16, 1), blk, 0, stream>>>(
        phi, ES, 0, 0, phiT, DIM, 0, 0, 1);
    concat_bias<<<dim3(12), blk, 0, stream>>>(bq, bkv, bqkv);

    // 1: fused QKV projection (N=3072, bf16 out)
    gemm_bf16<2,2,4,4,0,ushort><<<dim3(24, 32, 1), blk, 0, stream>>>(
        x_bf, DIM, 0, 0, WqkvT, DIM, 0, 0, bqkv, 0, 0,
        qkv_bf, 3 * DIM, 0, 0, DIM, 1, 1.f);

    // 2: vT[b,h][d][m] <- v slice of qkv (for K-contiguous AV B operand)
    transpose_cvt<ushort><<<dim3(1, 16, BATCH * HEADS), blk, 0, stream>>>(
        qkv_bf + 2 * DIM, 3 * DIM, (ll)SEQ * 3 * DIM, HD,
        vT, SEQ, (ll)HEADS * HD * SEQ, (ll)HD * SEQ, HEADS);

    // 3: scores p[b,n,h,m] = 0.125 * q_bh @ k_bh^T  (bf16 out, (b,n,h,m) layout)
    gemm_bf16<2,2,4,4,0,ushort><<<dim3(8, 8, BATCH * HEADS), blk, 0, stream>>>(
        qkv_bf, 3 * DIM, (ll)SEQ * 3 * DIM, HD,
        qkv_bf + DIM, 3 * DIM, (ll)SEQ * 3 * DIM, HD,
        nullptr, 0, 0,
        p_bf, HEADS * SEQ, (ll)SEQ * HEADS * SEQ, (ll)SEQ,
        HD, HEADS, 0.125f);

    // 4: softmax over m (in-place bf16) + fp32 bnmh attn output
    attn_softmax<<<dim3(SEQ, BATCH), blk, 0, stream>>>(p_bf, out_attn);

    // 5: ao[b,n,h*64+d] = p_bh @ vT_bh^T   (BM=128, BN=64; bf16 out)
    gemm_bf16<4,1,2,4,0,ushort><<<dim3(1, 8, BATCH * HEADS), blk, 0, stream>>>(
        p_bf, HEADS * SEQ, (ll)SEQ * HEADS * SEQ, (ll)SEQ,
        vT, SEQ, (ll)HEADS * HD * SEQ, (ll)HD * SEQ,
        nullptr, 0, 0,
        ao_bf, DIM, (ll)SEQ * DIM, HD,
        SEQ, HEADS, 1.f);

    // 6: output projection (fp32 out for LN residual)
    gemm_bf16<2,2,4,4,0,float><<<dim3(8, 32, 1), blk, 0, stream>>>(
        ao_bf, DIM, 0, 0, WpT, DIM, 0, 0, bp, 0, 0,
        po, DIM, 0, 0, DIM, 1, 1.f);
    // 7: x1 = LN(po + x)  (fp32 + bf16 copies)
    ln_kernel<<<dim3(NTOK), blk, 0, stream>>>(po, x, 1.0f, g1, b1, x1, x1_bf);

    // 7b: MoE weight transposes (into attn-dead regions) + x1T
    transpose_cvt<float><<<dim3(64, 16, 2), blk, 0, stream>>>(
        We1, HID, 0, (ll)DIM * HID, We1T, DIM, 0, (ll)HID * DIM, 2);
    transpose_cvt<float><<<dim3(16, 64, 2), blk, 0, stream>>>(
        We2, DIM, 0, (ll)HID * DIM, We2T, HID, 0, (ll)DIM * HID, 2);
    transpose_cvt<ushort><<<dim3(16, 16, BATCH), blk, 0, stream>>>(
        x1_bf, DIM, (ll)SEQ * DIM, 0, x1T, SEQ, (ll)DIM * SEQ, 0, 1);

    // 8: moe logits = x1 @ phi (fp32 out for softmaxes)
    gemm_bf16<2,2,4,4,0,float><<<dim3(8, 32, 1), blk, 0, stream>>>(
        x1_bf, DIM, 0, 0, phiT, DIM, 0, 0, nullptr, 0, 0,
        logit, ES, 0, 0, DIM, 1, 1.f);
    // 9-10: dispatch (transposed bf16) and combine (bf16) softmaxes
    col_softmax<<<dim3(BATCH, 16), blk, 0, stream>>>(logit, dispT);
    row_softmax<<<dim3(NTOK), blk, 0, stream>>>(logit, comb);

    // 11: slots[b] = dispT[b] @ x1T[b]^T   (ES x DIM, K=SEQ)
    gemm_bf16<2,2,4,4,0,ushort><<<dim3(8, 8, BATCH), blk, 0, stream>>>(
        dispT, SEQ, (ll)ES * SEQ, 0,
        x1T, SEQ, (ll)DIM * SEQ, 0,
        nullptr, 0, 0,
        slots, DIM, (ll)ES * DIM, 0,
        SEQ, 1, 1.f);

    // 12: hmid = gelu(slots @ We1 + be1), z = b*NEXP+e
    gemm_bf16<2,2,4,4,1,ushort><<<dim3(32, 4, BATCH * NEXP), blk, 0, stream>>>(
        slots, DIM, (ll)ES * DIM, (ll)NSLOT * DIM,
        We1T, DIM, 0, (ll)HID * DIM,
        be1, 0, HID,
        hmid, HID, (ll)ES * HID, (ll)NSLOT * HID,
        DIM, NEXP, 1.f);

    // 13: ymoe = hmid @ We2 + be2
    gemm_bf16<2,2,4,4,0,ushort><<<dim3(8, 4, BATCH * NEXP), blk, 0, stream>>>(
        hmid, HID, (ll)ES * HID, (ll)NSLOT * HID,
        We2T, HID, 0, (ll)DIM * HID,
        be2, 0, DIM,
        ymoe, DIM, (ll)ES * DIM, (ll)NSLOT * DIM,
        HID, NEXP, 1.f);

    // 13b: ymoeT[b][d][es] <- ymoe
    transpose_cvt<ushort><<<dim3(16, 16, BATCH), blk, 0, stream>>>(
        ymoe, DIM, (ll)ES * DIM, 0, ymoeT, ES, (ll)DIM * ES, 0, 1);

    // 14: moe[b] = comb[b] @ ymoeT[b]^T
    gemm_bf16<2,2,4,4,0,float><<<dim3(8, 8, BATCH), blk, 0, stream>>>(
        comb, ES, (ll)SEQ * ES, 0,
        ymoeT, ES, (ll)DIM * ES, 0,
        nullptr, 0, 0,
        moe, DIM, (ll)SEQ * DIM, 0,
        ES, 1, 1.f);

    // 15: y = LN(moe + 2*x1)
    ln_kernel<<<dim3(NTOK), blk, 0, stream>>>(moe, x1, 2.0f, g2, b2, out_y, nullptr);
}

// Round 4
// 1003.179 us; speedup vs baseline: 1.1867x; 1.0614x over previous
//
#include <hip/hip_runtime.h>
#include <math.h>

// Problem constants
#define BATCH 4
#define SEQ   1024
#define DIM   1024
#define HEADS 16
#define HD    64
#define NEXP  2
#define NSLOT 512
#define ES    1024       // NEXP*NSLOT
#define HID   4096
#define LNEPS 1e-5f
#define NTOK  (BATCH*SEQ)

typedef long long ll;
typedef unsigned short ushort;
typedef unsigned int uint;
typedef __attribute__((ext_vector_type(8))) short short8;   // 8 bf16 (4 VGPRs)
typedef __attribute__((ext_vector_type(4))) float f32x4;    // MFMA accum
typedef __attribute__((ext_vector_type(4))) unsigned short us4;

__device__ __forceinline__ ushort f2b(float f) {            // fp32 -> bf16 RNE
    uint u = __builtin_bit_cast(uint, f);
    u += 0x7FFFu + ((u >> 16) & 1u);
    return (ushort)(u >> 16);
}
__device__ __forceinline__ float b2f(ushort h) {
    uint u = ((uint)h) << 16;
    return __builtin_bit_cast(float, u);
}
__device__ __forceinline__ uint pk(float a, float b) {
    return (uint)f2b(a) | ((uint)f2b(b) << 16);
}
__device__ __forceinline__ float gelu_f(float v) {
    float x3 = v * v * v;
    return 0.5f * v * (1.f + tanhf(0.7978845608028654f * (v + 0.044715f * x3)));
}

// async global->LDS, 16B per lane.  LDS dest must be wave-uniform base + lane*16.
__device__ __forceinline__ void gload16(const ushort* g, ushort* l) {
    __builtin_amdgcn_global_load_lds(
        (const __attribute__((address_space(1))) unsigned int*)(const void*)g,
        (__attribute__((address_space(3))) unsigned int*)(void*)l,
        16, 0, 0);
}

// ---------------------------------------------------------------------------
// fp32 -> bf16 elementwise convert, 8 elems/thread (x: 4M elems, grid 2048)
// ---------------------------------------------------------------------------
__global__ __launch_bounds__(256) void cvt_bf16(
    const float* __restrict__ src, ushort* __restrict__ dst)
{
    int i = blockIdx.x * 256 + threadIdx.x;
    const float4* s = reinterpret_cast<const float4*>(src) + (ll)i * 2;
    float4 a = s[0], b = s[1];
    uint4 w;
    w.x = pk(a.x, a.y); w.y = pk(a.z, a.w);
    w.z = pk(b.x, b.y); w.w = pk(b.z, b.w);
    reinterpret_cast<uint4*>(dst)[i] = w;
}

// bias concat: o[0..1023] = a, o[1024..3071] = b   (grid 12)
__global__ __launch_bounds__(256) void concat_bias(
    const float* __restrict__ a, const float* __restrict__ b,
    float* __restrict__ o)
{
    int i = blockIdx.x * 256 + threadIdx.x;
    o[i] = (i < DIM) ? a[i] : b[i - DIM];
}

// ---------------------------------------------------------------------------
// Tiled transpose(+convert): dst[c][r] = bf16(src[r][c]).  64x64 tiles.
// ---------------------------------------------------------------------------
template<typename TS>
__global__ __launch_bounds__(256) void transpose_cvt(
    const TS* __restrict__ src, int ldsrc, ll sS1, ll sS2,
    ushort* __restrict__ dst, int lddst, ll sD1, ll sD2, int Z2)
{
    __shared__ ushort tile[64][68];
    const int z1 = blockIdx.z / Z2, z2 = blockIdx.z % Z2;
    src += z1 * sS1 + z2 * sS2;
    dst += z1 * sD1 + z2 * sD2;
    const int r0 = blockIdx.y * 64, c0 = blockIdx.x * 64;
    const int t = threadIdx.x;
    #pragma unroll
    for (int j = 0; j < 4; j++) {
        int idx = t + 256 * j;
        int r = idx >> 4, c = (idx & 15) * 4;
        if constexpr (sizeof(TS) == 4) {
            float4 v = *reinterpret_cast<const float4*>(src + (ll)(r0 + r) * ldsrc + c0 + c);
            tile[r][c]     = f2b(v.x);
            tile[r][c + 1] = f2b(v.y);
            tile[r][c + 2] = f2b(v.z);
            tile[r][c + 3] = f2b(v.w);
        } else {
            *reinterpret_cast<us4*>(&tile[r][c]) =
                *reinterpret_cast<const us4*>(src + (ll)(r0 + r) * ldsrc + c0 + c);
        }
    }
    __syncthreads();
    #pragma unroll
    for (int j = 0; j < 4; j++) {
        int idx = t + 256 * j;
        int rr = idx >> 4, cc = (idx & 15) * 4;
        us4 w;
        w.x = tile[cc][rr]; w.y = tile[cc + 1][rr];
        w.z = tile[cc + 2][rr]; w.w = tile[cc + 3][rr];
        *reinterpret_cast<us4*>(&dst[(ll)(c0 + rr) * lddst + r0 + cc]) = w;
    }
}

// ---------------------------------------------------------------------------
// MFMA bf16 GEMM (m97 structure), kept for scores (K=64) and AV (N=64).
// ---------------------------------------------------------------------------
template<int WR, int WC, int MI, int NI, int ACT, typename TC>
__global__ __launch_bounds__(256) void gemm_bf16(
    const ushort* __restrict__ A, int lda, ll sA1, ll sA2,
    const ushort* __restrict__ B, int ldb, ll sB1, ll sB2,
    const float* __restrict__ bias, ll sb1, ll sb2,
    TC* __restrict__ C, int ldc, ll sC1, ll sC2,
    int K, int Z2, float alpha)
{
    constexpr int BM = WR * MI * 16;
    constexpr int BN = WC * NI * 16;
    __shared__ alignas(16) ushort As[BM * 32];
    __shared__ alignas(16) ushort Bs[BN * 32];

    const int z1 = blockIdx.z / Z2, z2 = blockIdx.z % Z2;
    A += z1 * sA1 + z2 * sA2;
    B += z1 * sB1 + z2 * sB2;
    C += z1 * sC1 + z2 * sC2;

    const int t = threadIdx.x;
    const int m0 = blockIdx.y * BM, n0 = blockIdx.x * BN;
    const int lane = t & 63, wave = t >> 6;
    const int quad = lane >> 4, l16 = lane & 15;
    const int wm = wave / WC, wn = wave % WC;

    f32x4 acc[MI][NI] = {};

    for (int k0 = 0; k0 < K; k0 += 32) {
        #pragma unroll
        for (int i = 0; i < BM / 64; i++) {
            int seg = i * 256 + t;
            int row = seg >> 2, ke = (seg & 3) * 8;
            gload16(A + (ll)(m0 + row) * lda + (k0 + ke), &As[seg * 8]);
        }
        #pragma unroll
        for (int i = 0; i < BN / 64; i++) {
            int seg = i * 256 + t;
            int row = seg >> 2, ke = (seg & 3) * 8;
            gload16(B + (ll)(n0 + row) * ldb + (k0 + ke), &Bs[seg * 8]);
        }
        __syncthreads();

        short8 a[MI], b[NI];
        #pragma unroll
        for (int mi = 0; mi < MI; mi++)
            a[mi] = *reinterpret_cast<const short8*>(
                &As[(wm * MI * 16 + mi * 16 + l16) * 32 + quad * 8]);
        #pragma unroll
        for (int ni = 0; ni < NI; ni++)
            b[ni] = *reinterpret_cast<const short8*>(
                &Bs[(wn * NI * 16 + ni * 16 + l16) * 32 + quad * 8]);
        #pragma unroll
        for (int mi = 0; mi < MI; mi++)
            #pragma unroll
            for (int ni = 0; ni < NI; ni++)
                acc[mi][ni] = __builtin_amdgcn_mfma_f32_16x16x32_bf16(
                    a[mi], b[ni], acc[mi][ni], 0, 0, 0);
        __syncthreads();
    }

    const float* bz = bias ? (bias + z1 * sb1 + z2 * sb2) : nullptr;
    #pragma unroll
    for (int mi = 0; mi < MI; mi++) {
        #pragma unroll
        for (int ni = 0; ni < NI; ni++) {
            const int row = m0 + wm * MI * 16 + mi * 16 + quad * 4;
            const int col = n0 + wn * NI * 16 + ni * 16 + l16;
            const float bv = bz ? bz[col] : 0.f;
            #pragma unroll
            for (int r = 0; r < 4; r++) {
                float v = alpha * acc[mi][ni][r] + bv;
                if (ACT) v = gelu_f(v);
                if constexpr (sizeof(TC) == 2)
                    C[(ll)(row + r) * ldc + col] = f2b(v);
                else
                    C[(ll)(row + r) * ldc + col] = v;
            }
        }
    }
}

// ---------------------------------------------------------------------------
// gemm2: pipelined MFMA bf16 GEMM (T3+T4+T5: counted vmcnt, never 0 in loop;
// triple-buffered LDS so stage(kt+2) never touches a buffer being read;
// one raw s_barrier per K-tile; setprio around MFMA clusters).
//   C[M,N] = act(alpha * A@B^T + bias);  A [M][K], B [N][K] bf16 K-contig.
//   BK=64, 512 threads = 8 waves (WR x WC), wave C = 64 x (NI*16).
//   BM in {256,128}, BN = 128.  LDS = 3*(BM+BN)*64*2B (144/96 KiB).
// Hazard audit: buffer b=kt%3 is overwritten by stage(kt+3... i.e. kt+2 two
// iters later); at iter kt's collective s_barrier every wave has passed its
// iter-(kt-1) lgkmcnt(0), so all reads of buf[(kt-1)%3] = buf[(kt+2)%3] are
// retired before any wave issues the overwriting DMA after the barrier.
// vmcnt(LA+LB) at iter kt drains kt's own LA+LB loads (issued at kt-2) while
// keeping kt+1's in flight; final iter (no kt+1 staged) uses vmcnt(0).
// ---------------------------------------------------------------------------
template<int BM, int BN, int ACT, typename TC>
__global__ __launch_bounds__(512) void gemm2(
    const ushort* __restrict__ A, int lda, ll sA1, ll sA2,
    const ushort* __restrict__ B, int ldb, ll sB1, ll sB2,
    const float* __restrict__ bias, ll sb1, ll sb2,
    TC* __restrict__ C, int ldc, ll sC1, ll sC2,
    int K, int Z2, float alpha)
{
    constexpr int WR = BM / 64;          // waves along M (4 or 2)
    constexpr int WC = 8 / WR;           // 2 or 4
    constexpr int MI = 4;                // 64 rows per wave
    constexpr int NI = BN / WC / 16;     // 4 or 2
    constexpr int NH = NI / 2 ? NI / 2 : 1;  // frags per phase (2 or 1)
    constexpr int LA = BM / 64;          // A stage instrs per K-tile
    constexpr int LB = BN / 64;          // B stage instrs per K-tile

    __shared__ alignas(16) ushort As[3][BM * 64];
    __shared__ alignas(16) ushort Bs[3][BN * 64];

    const int z1 = blockIdx.z / Z2, z2 = blockIdx.z % Z2;
    A += z1 * sA1 + z2 * sA2;
    B += z1 * sB1 + z2 * sB2;
    C += z1 * sC1 + z2 * sC2;

    const int t = threadIdx.x;
    const int lane = t & 63, wave = t >> 6;
    const int quad = lane >> 4, l16 = lane & 15;
    const int wm = wave / WC, wn = wave % WC;
    const int m0 = blockIdx.y * BM, n0 = blockIdx.x * BN;

    auto stageA = [&](int kt) {
        const ushort* src = A + (ll)m0 * lda + kt * 64;
        ushort* dst = As[kt % 3];
        #pragma unroll
        for (int j = 0; j < LA; j++) {
            int seg = j * 512 + t;
            int row = seg >> 3, kk = (seg & 7) * 8;
            gload16(src + (ll)row * lda + kk, dst + seg * 8);
        }
    };
    auto stageB = [&](int kt) {
        const ushort* src = B + (ll)n0 * ldb + kt * 64;
        ushort* dst = Bs[kt % 3];
        #pragma unroll
        for (int j = 0; j < LB; j++) {
            int seg = j * 512 + t;
            int row = seg >> 3, kk = (seg & 7) * 8;
            gload16(src + (ll)row * ldb + kk, dst + seg * 8);
        }
    };

    f32x4 acc[MI][NI] = {};
    const int NK = K / 64;

    stageA(0); stageB(0);
    if (NK > 1) { stageA(1); stageB(1); }

    for (int kt = 0; kt < NK; kt++) {
        // drain this K-tile's loads; keep the next tile's in flight
        if (kt + 1 < NK)
            asm volatile("s_waitcnt vmcnt(%0)" :: "n"(LA + LB) : "memory");
        else
            asm volatile("s_waitcnt vmcnt(0)" ::: "memory");
        __builtin_amdgcn_sched_barrier(0);
        __builtin_amdgcn_s_barrier();
        __builtin_amdgcn_sched_barrier(0);

        const ushort* Abuf = As[kt % 3];
        const ushort* Bbuf = Bs[kt % 3];

        // ---- phase 0: all A frags + first half of B frags, then MFMA ----
        short8 a[MI][2], b0[NH][2];
        #pragma unroll
        for (int mi = 0; mi < MI; mi++)
            #pragma unroll
            for (int kh = 0; kh < 2; kh++)
                a[mi][kh] = *reinterpret_cast<const short8*>(
                    &Abuf[(wm * 64 + mi * 16 + l16) * 64 + kh * 32 + quad * 8]);
        #pragma unroll
        for (int ni = 0; ni < NH; ni++)
            #pragma unroll
            for (int kh = 0; kh < 2; kh++)
                b0[ni][kh] = *reinterpret_cast<const short8*>(
                    &Bbuf[(wn * NI * 16 + ni * 16 + l16) * 64 + kh * 32 + quad * 8]);
        if (kt + 2 < NK) stageA(kt + 2);
        asm volatile("s_waitcnt lgkmcnt(0)" ::: "memory");
        __builtin_amdgcn_sched_barrier(0);
        __builtin_amdgcn_s_setprio(1);
        #pragma unroll
        for (int mi = 0; mi < MI; mi++)
            #pragma unroll
            for (int ni = 0; ni < NH; ni++)
                #pragma unroll
                for (int kh = 0; kh < 2; kh++)
                    acc[mi][ni] = __builtin_amdgcn_mfma_f32_16x16x32_bf16(
                        a[mi][kh], b0[ni][kh], acc[mi][ni], 0, 0, 0);
        __builtin_amdgcn_s_setprio(0);
        __builtin_amdgcn_sched_barrier(0);

        // ---- phase 1: second half of B frags, then MFMA ----
        short8 b1[NH][2];
        #pragma unroll
        for (int ni = 0; ni < NH; ni++)
            #pragma unroll
            for (int kh = 0; kh < 2; kh++)
                b1[ni][kh] = *reinterpret_cast<const short8*>(
                    &Bbuf[(wn * NI * 16 + (NH + ni) * 16 + l16) * 64 + kh * 32 + quad * 8]);
        if (kt + 2 < NK) stageB(kt + 2);
        asm volatile("s_waitcnt lgkmcnt(0)" ::: "memory");
        __builtin_amdgcn_sched_barrier(0);
        __builtin_amdgcn_s_setprio(1);
        #pragma unroll
        for (int mi = 0; mi < MI; mi++)
            #pragma unroll
            for (int ni = 0; ni < NH; ni++)
                #pragma unroll
                for (int kh = 0; kh < 2; kh++)
                    acc[mi][NH + ni] = __builtin_amdgcn_mfma_f32_16x16x32_bf16(
                        a[mi][kh], b1[ni][kh], acc[mi][NH + ni], 0, 0, 0);
        __builtin_amdgcn_s_setprio(0);
        __builtin_amdgcn_sched_barrier(0);
    }

    const float* bz = bias ? (bias + z1 * sb1 + z2 * sb2) : nullptr;
    #pragma unroll
    for (int mi = 0; mi < MI; mi++) {
        #pragma unroll
        for (int ni = 0; ni < NI; ni++) {
            const int row = m0 + wm * 64 + mi * 16 + quad * 4;
            const int col = n0 + wn * NI * 16 + ni * 16 + l16;
            const float bv = bz ? bz[col] : 0.f;
            #pragma unroll
            for (int r = 0; r < 4; r++) {
                float v = alpha * acc[mi][ni][r] + bv;
                if (ACT) v = gelu_f(v);
                if constexpr (sizeof(TC) == 2)
                    C[(ll)(row + r) * ldc + col] = f2b(v);
                else
                    C[(ll)(row + r) * ldc + col] = v;
            }
        }
    }
}

// ---------------------------------------------------------------------------
// Attention softmax over m, v3 (unchanged from round 3).
// ---------------------------------------------------------------------------
__global__ __launch_bounds__(256) void attn_softmax(
    ushort* __restrict__ p, float* __restrict__ attn_out)
{
    __shared__ float tile[16][1024];
    const int n = blockIdx.x, b = blockIdx.y;
    const int t = threadIdx.x;
    const int lane = t & 63, w = t >> 6;
    ushort* base = p + ((ll)(b * SEQ + n) * HEADS) * SEQ;
    #pragma unroll 1
    for (int g = 0; g < 4; g++) {
        const int h = g * 4 + w;
        ushort* row = base + (ll)h * SEQ + lane * 16;
        uint4 r0 = reinterpret_cast<const uint4*>(row)[0];
        uint4 r1 = reinterpret_cast<const uint4*>(row)[1];
        uint rr[8] = {r0.x, r0.y, r0.z, r0.w, r1.x, r1.y, r1.z, r1.w};
        float v[16];
        float m = -3.0e38f;
        #pragma unroll
        for (int j = 0; j < 8; j++) {
            v[2 * j]     = b2f((ushort)(rr[j] & 0xFFFFu));
            v[2 * j + 1] = b2f((ushort)(rr[j] >> 16));
            m = fmaxf(m, fmaxf(v[2 * j], v[2 * j + 1]));
        }
        #pragma unroll
        for (int o = 32; o; o >>= 1) m = fmaxf(m, __shfl_xor(m, o));
        float s = 0.f;
        #pragma unroll
        for (int j = 0; j < 16; j++) { v[j] = __expf(v[j] - m); s += v[j]; }
        #pragma unroll
        for (int o = 32; o; o >>= 1) s += __shfl_xor(s, o);
        const float inv = 1.f / s;
        #pragma unroll
        for (int j = 0; j < 16; j++) v[j] *= inv;
        uint pw[8];
        #pragma unroll
        for (int j = 0; j < 8; j++) pw[j] = pk(v[2 * j], v[2 * j + 1]);
        uint4 w0, w1;
        w0.x = pw[0]; w0.y = pw[1]; w0.z = pw[2]; w0.w = pw[3];
        w1.x = pw[4]; w1.y = pw[5]; w1.z = pw[6]; w1.w = pw[7];
        reinterpret_cast<uint4*>(row)[0] = w0;
        reinterpret_cast<uint4*>(row)[1] = w1;
        #pragma unroll
        for (int jj = 0; jj < 4; jj++) {
            float4 f4;
            f4.x = v[4 * jj]; f4.y = v[4 * jj + 1];
            f4.z = v[4 * jj + 2]; f4.w = v[4 * jj + 3];
            *reinterpret_cast<float4*>(&tile[h][(jj * 64 + lane) * 4]) = f4;
        }
    }
    __syncthreads();
    float* outp = attn_out + ((ll)b * SEQ + n) * SEQ * HEADS;
    #pragma unroll
    for (int jj = 0; jj < 4; jj++) {
        const int mm = t + 256 * jj;
        const int gm = mm >> 2;
        const int fi = ((gm & 3) * 64 + (gm >> 2)) * 4 + (mm & 3);
        float o16[16];
        #pragma unroll
        for (int h = 0; h < 16; h++) o16[h] = tile[h][fi];
        float4* dst = reinterpret_cast<float4*>(outp + (ll)mm * HEADS);
        #pragma unroll
        for (int q = 0; q < 4; q++) {
            float4 o4;
            o4.x = o16[4 * q]; o4.y = o16[4 * q + 1];
            o4.z = o16[4 * q + 2]; o4.w = o16[4 * q + 3];
            dst[q] = o4;
        }
    }
}

// ---------------------------------------------------------------------------
// LayerNorm (vectorized), optional bf16 copy.
// ---------------------------------------------------------------------------
__global__ __launch_bounds__(256) void ln_kernel(
    const float* __restrict__ a, const float* __restrict__ b, float coef,
    const float* __restrict__ g, const float* __restrict__ beta,
    float* __restrict__ out, ushort* __restrict__ out_bf)
{
    const int row = blockIdx.x;
    const int t = threadIdx.x;
    float4 av = reinterpret_cast<const float4*>(a + (ll)row * DIM)[t];
    float4 bv = reinterpret_cast<const float4*>(b + (ll)row * DIM)[t];
    float4 v;
    v.x = av.x + coef * bv.x; v.y = av.y + coef * bv.y;
    v.z = av.z + coef * bv.z; v.w = av.w + coef * bv.w;
    float s1 = v.x + v.y + v.z + v.w;
    float s2 = v.x * v.x + v.y * v.y + v.z * v.z + v.w * v.w;
    __shared__ float red[8];
    #pragma unroll
    for (int o = 32; o; o >>= 1) { s1 += __shfl_xor(s1, o); s2 += __shfl_xor(s2, o); }
    int w = t >> 6;
    if ((t & 63) == 0) { red[w] = s1; red[4 + w] = s2; }
    __syncthreads();
    s1 = red[0] + red[1] + red[2] + red[3];
    s2 = red[4] + red[5] + red[6] + red[7];
    float mu = s1 * (1.f / DIM);
    float var = s2 * (1.f / DIM) - mu * mu;
    float rs = rsqrtf(var + LNEPS);
    float4 gv = reinterpret_cast<const float4*>(g)[t];
    float4 be = reinterpret_cast<const float4*>(beta)[t];
    float4 o;
    o.x = (v.x - mu) * rs * gv.x + be.x;
    o.y = (v.y - mu) * rs * gv.y + be.y;
    o.z = (v.z - mu) * rs * gv.z + be.z;
    o.w = (v.w - mu) * rs * gv.w + be.w;
    reinterpret_cast<float4*>(out + (ll)row * DIM)[t] = o;
    if (out_bf) {
        us4 hv;
        hv.x = f2b(o.x); hv.y = f2b(o.y); hv.z = f2b(o.z); hv.w = f2b(o.w);
        reinterpret_cast<us4*>(out_bf + (ll)row * DIM)[t] = hv;
    }
}

// ---------------------------------------------------------------------------
// dispatch softmax over n -> transposed bf16 dispT[b][es][n]
// ---------------------------------------------------------------------------
__global__ __launch_bounds__(256) void col_softmax(
    const float* __restrict__ logits, ushort* __restrict__ dispT)
{
    const int b = blockIdx.x, cc = blockIdx.y;
    const int cl = threadIdx.x & 63;
    const int c = cc * 64 + cl;
    const int rg = threadIdx.x >> 6;
    const float* L = logits + (ll)b * SEQ * ES + c;
    ushort* DT = dispT + (ll)b * ES * SEQ + (ll)c * SEQ;
    __shared__ float red[4][64];
    float m = -3.0e38f;
    for (int n = rg; n < SEQ; n += 4) m = fmaxf(m, L[(ll)n * ES]);
    red[rg][cl] = m;
    __syncthreads();
    m = fmaxf(fmaxf(red[0][cl], red[1][cl]), fmaxf(red[2][cl], red[3][cl]));
    __syncthreads();
    float s = 0.f;
    for (int n = rg; n < SEQ; n += 4) s += __expf(L[(ll)n * ES] - m);
    red[rg][cl] = s;
    __syncthreads();
    s = red[0][cl] + red[1][cl] + red[2][cl] + red[3][cl];
    float inv = 1.f / s;
    for (int n = rg; n < SEQ; n += 4)
        DT[n] = f2b(__expf(L[(ll)n * ES] - m) * inv);
}

// combine = softmax over es (rows of 1024), bf16 out
__global__ __launch_bounds__(256) void row_softmax(
    const float* __restrict__ logits, ushort* __restrict__ comb)
{
    const int row = blockIdx.x;
    const float* L = logits + (ll)row * ES;
    ushort* O = comb + (ll)row * ES;
    float v[4];
    float m = -3.0e38f;
    #pragma unroll
    for (int j = 0; j < 4; j++) { v[j] = L[threadIdx.x + 256 * j]; m = fmaxf(m, v[j]); }
    __shared__ float red[8];
    #pragma unroll
    for (int o = 32; o; o >>= 1) m = fmaxf(m, __shfl_xor(m, o));
    int w = threadIdx.x >> 6;
    if ((threadIdx.x & 63) == 0) red[w] = m;
    __syncthreads();
    m = fmaxf(fmaxf(red[0], red[1]), fmaxf(red[2], red[3]));
    __syncthreads();
    float s = 0.f;
    #pragma unroll
    for (int j = 0; j < 4; j++) { v[j] = __expf(v[j] - m); s += v[j]; }
    #pragma unroll
    for (int o = 32; o; o >>= 1) s += __shfl_xor(s, o);
    if ((threadIdx.x & 63) == 0) red[4 + w] = s;
    __syncthreads();
    s = red[4] + red[5] + red[6] + red[7];
    float inv = 1.f / s;
    #pragma unroll
    for (int j = 0; j < 4; j++) O[threadIdx.x + 256 * j] = f2b(v[j] * inv);
}

// ---------------------------------------------------------------------------
extern "C" void kernel_launch(void* const* d_in, const int* in_sizes, int n_in,
                              void* d_out, int out_size, void* d_ws, size_t ws_size,
                              hipStream_t stream)
{
    const float* x   = (const float*)d_in[0];
    const float* Wq  = (const float*)d_in[1];
    const float* bq  = (const float*)d_in[2];
    const float* Wkv = (const float*)d_in[3];
    const float* bkv = (const float*)d_in[4];
    const float* Wp  = (const float*)d_in[5];
    const float* bp  = (const float*)d_in[6];
    const float* g1  = (const float*)d_in[7];
    const float* b1  = (const float*)d_in[8];
    const float* phi = (const float*)d_in[9];
    const float* We1 = (const float*)d_in[10];
    const float* be1 = (const float*)d_in[11];
    const float* We2 = (const float*)d_in[12];
    const float* be2 = (const float*)d_in[13];
    const float* g2  = (const float*)d_in[14];
    const float* b2  = (const float*)d_in[15];

    float* out_y    = (float*)d_out;
    float* out_attn = out_y + (ll)BATCH * SEQ * DIM;

    // Workspace layout (float offsets, M1 = 1M floats).  Peak ~46.5M fl = 186 MB.
    const ll M1 = 1024 * 1024;
    float*  ws     = (float*)d_ws;
    ushort* x_bf   = (ushort*)(ws);                 // [0, 2M)
    ushort* WqkvT  = (ushort*)(ws + 2 * M1);        // [2, 3.5M)   3072x1024 bf16
    ushort* WpT    = (ushort*)(ws + 7 * M1 / 2);    // [3.5, 4M)
    ushort* phiT   = (ushort*)(ws + 4 * M1);        // [4, 4.5M)
    ushort* qkv_bf = (ushort*)(ws + 9 * M1 / 2);    // [4.5, 10.5M) 4096x3072 bf16
    ushort* vT     = (ushort*)(ws + 21 * M1 / 2);   // [10.5, 12.5M)
    ushort* p_bf   = (ushort*)(ws + 25 * M1 / 2);   // [12.5, 44.5M)
    float*  po     = ws + 25 * M1 / 2;              //   (after AV)
    ushort* ao_bf  = (ushort*)(ws + 89 * M1 / 2);   // [44.5, 46.5M)
    ushort* ymoeT  = (ushort*)(ws + 89 * M1 / 2);   //   (phase 2 alias)
    float*  x1     = ws + 33 * M1 / 2;              // [16.5, 20.5M)
    ushort* x1_bf  = (ushort*)(ws + 41 * M1 / 2);   // [20.5, 22.5M)
    ushort* x1T    = (ushort*)(ws + 45 * M1 / 2);   // [22.5, 24.5M)
    float*  logit  = ws + 49 * M1 / 2;              // [24.5, 28.5M)
    ushort* dispT  = (ushort*)(ws + 57 * M1 / 2);   // [28.5, 30.5M)
    ushort* comb   = (ushort*)(ws + 61 * M1 / 2);   // [30.5, 32.5M)
    ushort* slots  = (ushort*)(ws + 65 * M1 / 2);   // [32.5, 34.5M)
    ushort* hmid   = (ushort*)(ws + 69 * M1 / 2);   // [34.5, 42.5M)
    ushort* ymoe   = (ushort*)(ws + 85 * M1 / 2);   // [42.5, 44.5M)
    ushort* We1T   = (ushort*)(ws + 9 * M1 / 2);    // [4.5, 8.5M)  phase 2
    ushort* We2T   = (ushort*)(ws + 17 * M1 / 2);   // [8.5, 12.5M) phase 2
    float*  bqkv   = ws + 93 * M1 / 2;              // [46.5M, +3072)
    float*  moe    = ws;                            // [0, 4M) phase 2

    dim3 blk(256), blk5(512);

    // 0: bf16 conversions / weight transposes for the attention phase
    cvt_bf16<<<dim3(2048), blk, 0, stream>>>(x, x_bf);
    transpose_cvt<float><<<dim3(16, 16, 1), blk, 0, stream>>>(
        Wq, DIM, 0, 0, WqkvT, DIM, 0, 0, 1);
    transpose_cvt<float><<<dim3(32, 16, 1), blk, 0, stream>>>(
        Wkv, 2 * DIM, 0, 0, WqkvT + (ll)DIM * DIM, DIM, 0, 0, 1);
    transpose_cvt<float><<<dim3(16, 16, 1), blk, 0, stream>>>(
        Wp, DIM, 0, 0, WpT, DIM, 0, 0, 1);
    transpose_cvt<float><<<dim3(16, 16, 1), blk, 0, stream>>>(
        phi, ES, 0, 0, phiT, DIM, 0, 0, 1);
    concat_bias<<<dim3(12), blk, 0, stream>>>(bq, bkv, bqkv);

    // 1: fused QKV projection (N=3072, bf16 out)  [pipelined 256x128]
    gemm2<256,128,0,ushort><<<dim3(24, 16, 1), blk5, 0, stream>>>(
        x_bf, DIM, 0, 0, WqkvT, DIM, 0, 0, bqkv, 0, 0,
        qkv_bf, 3 * DIM, 0, 0, DIM, 1, 1.f);

    // 2: vT[b,h][d][m] <- v slice of qkv
    transpose_cvt<ushort><<<dim3(1, 16, BATCH * HEADS), blk, 0, stream>>>(
        qkv_bf + 2 * DIM, 3 * DIM, (ll)SEQ * 3 * DIM, HD,
        vT, SEQ, (ll)HEADS * HD * SEQ, (ll)HD * SEQ, HEADS);

    // 3: scores p[b,n,h,m] = 0.125 * q_bh @ k_bh^T  (K=64: keep m97 kernel)
    gemm_bf16<2,2,4,4,0,ushort><<<dim3(8, 8, BATCH * HEADS), blk, 0, stream>>>(
        qkv_bf, 3 * DIM, (ll)SEQ * 3 * DIM, HD,
        qkv_bf + DIM, 3 * DIM, (ll)SEQ * 3 * DIM, HD,
        nullptr, 0, 0,
        p_bf, HEADS * SEQ, (ll)SEQ * HEADS * SEQ, (ll)SEQ,
        HD, HEADS, 0.125f);

    // 4: softmax over m (in-place bf16) + fp32 bnmh attn output
    attn_softmax<<<dim3(SEQ, BATCH), blk, 0, stream>>>(p_bf, out_attn);

    // 5: ao = p_bh @ vT_bh^T   (N=64: keep m97 kernel)
    gemm_bf16<4,1,2,4,0,ushort><<<dim3(1, 8, BATCH * HEADS), blk, 0, stream>>>(
        p_bf, HEADS * SEQ, (ll)SEQ * HEADS * SEQ, (ll)SEQ,
        vT, SEQ, (ll)HEADS * HD * SEQ, (ll)HD * SEQ,
        nullptr, 0, 0,
        ao_bf, DIM, (ll)SEQ * DIM, HD,
        SEQ, HEADS, 1.f);

    // 6: output projection (fp32 out)  [pipelined 128x128]
    gemm2<128,128,0,float><<<dim3(8, 32, 1), blk5, 0, stream>>>(
        ao_bf, DIM, 0, 0, WpT, DIM, 0, 0, bp, 0, 0,
        po, DIM, 0, 0, DIM, 1, 1.f);
    // 7: x1 = LN(po + x)
    ln_kernel<<<dim3(NTOK), blk, 0, stream>>>(po, x, 1.0f, g1, b1, x1, x1_bf);

    // 7b: MoE weight transposes + x1T
    transpose_cvt<float><<<dim3(64, 16, 2), blk, 0, stream>>>(
        We1, HID, 0, (ll)DIM * HID, We1T, DIM, 0, (ll)HID * DIM, 2);
    transpose_cvt<float><<<dim3(16, 64, 2), blk, 0, stream>>>(
        We2, DIM, 0, (ll)HID * DIM, We2T, HID, 0, (ll)DIM * HID, 2);
    transpose_cvt<ushort><<<dim3(16, 16, BATCH), blk, 0, stream>>>(
        x1_bf, DIM, (ll)SEQ * DIM, 0, x1T, SEQ, (ll)DIM * SEQ, 0, 1);

    // 8: moe logits = x1 @ phi (fp32 out)  [pipelined 128x128]
    gemm2<128,128,0,float><<<dim3(8, 32, 1), blk5, 0, stream>>>(
        x1_bf, DIM, 0, 0, phiT, DIM, 0, 0, nullptr, 0, 0,
        logit, ES, 0, 0, DIM, 1, 1.f);
    // 9-10: dispatch / combine softmaxes
    col_softmax<<<dim3(BATCH, 16), blk, 0, stream>>>(logit, dispT);
    row_softmax<<<dim3(NTOK), blk, 0, stream>>>(logit, comb);

    // 11: slots[b] = dispT[b] @ x1T[b]^T   [pipelined 128x128]
    gemm2<128,128,0,ushort><<<dim3(8, 8, BATCH), blk5, 0, stream>>>(
        dispT, SEQ, (ll)ES * SEQ, 0,
        x1T, SEQ, (ll)DIM * SEQ, 0,
        nullptr, 0, 0,
        slots, DIM, (ll)ES * DIM, 0,
        SEQ, 1, 1.f);

    // 12: hmid = gelu(slots @ We1 + be1)   [pipelined 256x128]
    gemm2<256,128,1,ushort><<<dim3(32, 2, BATCH * NEXP), blk5, 0, stream>>>(
        slots, DIM, (ll)ES * DIM, (ll)NSLOT * DIM,
        We1T, DIM, 0, (ll)HID * DIM,
        be1, 0, HID,
        hmid, HID, (ll)ES * HID, (ll)NSLOT * HID,
        DIM, NEXP, 1.f);

    // 13: ymoe = hmid @ We2 + be2   [pipelined 128x128]
    gemm2<128,128,0,ushort><<<dim3(8, 4, BATCH * NEXP), blk5, 0, stream>>>(
        hmid, HID, (ll)ES * HID, (ll)NSLOT * HID,
        We2T, HID, 0, (ll)DIM * HID,
        be2, 0, DIM,
        ymoe, DIM, (ll)ES * DIM, (ll)NSLOT * DIM,
        HID, NEXP, 1.f);

    // 13b: ymoeT[b][d][es] <- ymoe
    transpose_cvt<ushort><<<dim3(16, 16, BATCH), blk, 0, stream>>>(
        ymoe, DIM, (ll)ES * DIM, 0, ymoeT, ES, (ll)DIM * ES, 0, 1);

    // 14: moe[b] = comb[b] @ ymoeT[b]^T   [pipelined 128x128]
    gemm2<128,128,0,float><<<dim3(8, 8, BATCH), blk5, 0, stream>>>(
        comb, ES, (ll)SEQ * ES, 0,
        ymoeT, ES, (ll)DIM * ES, 0,
        nullptr, 0, 0,
        moe, DIM, (ll)SEQ * DIM, 0,
        ES, 1, 1.f);

    // 15: y = LN(moe + 2*x1)
    ln_kernel<<<dim3(NTOK), blk, 0, stream>>>(moe, x1, 2.0f, g2, b2, out_y, nullptr);
}

// Round 5
// 883.636 us; speedup vs baseline: 1.3472x; 1.1353x over previous
//
#include <hip/hip_runtime.h>
#include <math.h>

// Problem constants
#define BATCH 4
#define SEQ   1024
#define DIM   1024
#define HEADS 16
#define HD    64
#define NEXP  2
#define NSLOT 512
#define ES    1024       // NEXP*NSLOT
#define HID   4096
#define LNEPS 1e-5f
#define NTOK  (BATCH*SEQ)

typedef long long ll;
typedef unsigned short ushort;
typedef unsigned int uint;
typedef __attribute__((ext_vector_type(8))) short short8;   // 8 bf16 (4 VGPRs)
typedef __attribute__((ext_vector_type(4))) float f32x4;    // MFMA accum
typedef __attribute__((ext_vector_type(4))) unsigned short us4;

__device__ __forceinline__ ushort f2b(float f) {            // fp32 -> bf16 RNE
    uint u = __builtin_bit_cast(uint, f);
    u += 0x7FFFu + ((u >> 16) & 1u);
    return (ushort)(u >> 16);
}
__device__ __forceinline__ float b2f(ushort h) {
    uint u = ((uint)h) << 16;
    return __builtin_bit_cast(float, u);
}
__device__ __forceinline__ uint pk(float a, float b) {
    return (uint)f2b(a) | ((uint)f2b(b) << 16);
}
__device__ __forceinline__ float gelu_f(float v) {
    float x3 = v * v * v;
    return 0.5f * v * (1.f + tanhf(0.7978845608028654f * (v + 0.044715f * x3)));
}

// async global->LDS, 16B per lane.  LDS dest must be wave-uniform base + lane*16.
__device__ __forceinline__ void gload16(const ushort* g, ushort* l) {
    __builtin_amdgcn_global_load_lds(
        (const __attribute__((address_space(1))) unsigned int*)(const void*)g,
        (__attribute__((address_space(3))) unsigned int*)(void*)l,
        16, 0, 0);
}

// ---------------------------------------------------------------------------
// fp32 -> bf16 elementwise convert, 8 elems/thread (x: 4M elems, grid 2048)
// ---------------------------------------------------------------------------
__global__ __launch_bounds__(256) void cvt_bf16(
    const float* __restrict__ src, ushort* __restrict__ dst)
{
    int i = blockIdx.x * 256 + threadIdx.x;
    const float4* s = reinterpret_cast<const float4*>(src) + (ll)i * 2;
    float4 a = s[0], b = s[1];
    uint4 w;
    w.x = pk(a.x, a.y); w.y = pk(a.z, a.w);
    w.z = pk(b.x, b.y); w.w = pk(b.z, b.w);
    reinterpret_cast<uint4*>(dst)[i] = w;
}

// bias concat: o[0..1023] = a, o[1024..3071] = b   (grid 12)
__global__ __launch_bounds__(256) void concat_bias(
    const float* __restrict__ a, const float* __restrict__ b,
    float* __restrict__ o)
{
    int i = blockIdx.x * 256 + threadIdx.x;
    o[i] = (i < DIM) ? a[i] : b[i - DIM];
}

// ---------------------------------------------------------------------------
// Tiled transpose(+convert): dst[c][r] = TD(src[r][c]).  64x64 tiles.
// TS in {float, ushort}; TD in {float, ushort}.
// ---------------------------------------------------------------------------
template<typename TS, typename TD>
__global__ __launch_bounds__(256) void transpose_cvt(
    const TS* __restrict__ src, int ldsrc, ll sS1, ll sS2,
    TD* __restrict__ dst, int lddst, ll sD1, ll sD2, int Z2)
{
    __shared__ TD tile[64][68];
    const int z1 = blockIdx.z / Z2, z2 = blockIdx.z % Z2;
    src += z1 * sS1 + z2 * sS2;
    dst += z1 * sD1 + z2 * sD2;
    const int r0 = blockIdx.y * 64, c0 = blockIdx.x * 64;
    const int t = threadIdx.x;
    #pragma unroll
    for (int j = 0; j < 4; j++) {
        int idx = t + 256 * j;
        int r = idx >> 4, c = (idx & 15) * 4;
        if constexpr (sizeof(TS) == 4 && sizeof(TD) == 2) {
            float4 v = *reinterpret_cast<const float4*>(src + (ll)(r0 + r) * ldsrc + c0 + c);
            tile[r][c]     = f2b(v.x);
            tile[r][c + 1] = f2b(v.y);
            tile[r][c + 2] = f2b(v.z);
            tile[r][c + 3] = f2b(v.w);
        } else if constexpr (sizeof(TS) == 4 && sizeof(TD) == 4) {
            float4 v = *reinterpret_cast<const float4*>(src + (ll)(r0 + r) * ldsrc + c0 + c);
            *reinterpret_cast<float4*>(&tile[r][c]) = v;
        } else {
            *reinterpret_cast<us4*>(&tile[r][c]) =
                *reinterpret_cast<const us4*>(src + (ll)(r0 + r) * ldsrc + c0 + c);
        }
    }
    __syncthreads();
    #pragma unroll
    for (int j = 0; j < 4; j++) {
        int idx = t + 256 * j;
        int rr = idx >> 4, cc = (idx & 15) * 4;
        if constexpr (sizeof(TD) == 2) {
            us4 w;
            w.x = tile[cc][rr]; w.y = tile[cc + 1][rr];
            w.z = tile[cc + 2][rr]; w.w = tile[cc + 3][rr];
            *reinterpret_cast<us4*>(&dst[(ll)(c0 + rr) * lddst + r0 + cc]) = w;
        } else {
            float4 w;
            w.x = tile[cc][rr]; w.y = tile[cc + 1][rr];
            w.z = tile[cc + 2][rr]; w.w = tile[cc + 3][rr];
            *reinterpret_cast<float4*>(&dst[(ll)(c0 + rr) * lddst + r0 + cc]) = w;
        }
    }
}

// ---------------------------------------------------------------------------
// MFMA bf16 GEMM (m97 structure), kept for scores (K=64).
// ---------------------------------------------------------------------------
template<int WR, int WC, int MI, int NI, int ACT, typename TC>
__global__ __launch_bounds__(256) void gemm_bf16(
    const ushort* __restrict__ A, int lda, ll sA1, ll sA2,
    const ushort* __restrict__ B, int ldb, ll sB1, ll sB2,
    const float* __restrict__ bias, ll sb1, ll sb2,
    TC* __restrict__ C, int ldc, ll sC1, ll sC2,
    int K, int Z2, float alpha)
{
    constexpr int BM = WR * MI * 16;
    constexpr int BN = WC * NI * 16;
    __shared__ alignas(16) ushort As[BM * 32];
    __shared__ alignas(16) ushort Bs[BN * 32];

    const int z1 = blockIdx.z / Z2, z2 = blockIdx.z % Z2;
    A += z1 * sA1 + z2 * sA2;
    B += z1 * sB1 + z2 * sB2;
    C += z1 * sC1 + z2 * sC2;

    const int t = threadIdx.x;
    const int m0 = blockIdx.y * BM, n0 = blockIdx.x * BN;
    const int lane = t & 63, wave = t >> 6;
    const int quad = lane >> 4, l16 = lane & 15;
    const int wm = wave / WC, wn = wave % WC;

    f32x4 acc[MI][NI] = {};

    for (int k0 = 0; k0 < K; k0 += 32) {
        #pragma unroll
        for (int i = 0; i < BM / 64; i++) {
            int seg = i * 256 + t;
            int row = seg >> 2, ke = (seg & 3) * 8;
            gload16(A + (ll)(m0 + row) * lda + (k0 + ke), &As[seg * 8]);
        }
        #pragma unroll
        for (int i = 0; i < BN / 64; i++) {
            int seg = i * 256 + t;
            int row = seg >> 2, ke = (seg & 3) * 8;
            gload16(B + (ll)(n0 + row) * ldb + (k0 + ke), &Bs[seg * 8]);
        }
        __syncthreads();

        short8 a[MI], b[NI];
        #pragma unroll
        for (int mi = 0; mi < MI; mi++)
            a[mi] = *reinterpret_cast<const short8*>(
                &As[(wm * MI * 16 + mi * 16 + l16) * 32 + quad * 8]);
        #pragma unroll
        for (int ni = 0; ni < NI; ni++)
            b[ni] = *reinterpret_cast<const short8*>(
                &Bs[(wn * NI * 16 + ni * 16 + l16) * 32 + quad * 8]);
        #pragma unroll
        for (int mi = 0; mi < MI; mi++)
            #pragma unroll
            for (int ni = 0; ni < NI; ni++)
                acc[mi][ni] = __builtin_amdgcn_mfma_f32_16x16x32_bf16(
                    a[mi], b[ni], acc[mi][ni], 0, 0, 0);
        __syncthreads();
    }

    const float* bz = bias ? (bias + z1 * sb1 + z2 * sb2) : nullptr;
    #pragma unroll
    for (int mi = 0; mi < MI; mi++) {
        #pragma unroll
        for (int ni = 0; ni < NI; ni++) {
            const int row = m0 + wm * MI * 16 + mi * 16 + quad * 4;
            const int col = n0 + wn * NI * 16 + ni * 16 + l16;
            const float bv = bz ? bz[col] : 0.f;
            #pragma unroll
            for (int r = 0; r < 4; r++) {
                float v = alpha * acc[mi][ni][r] + bv;
                if (ACT) v = gelu_f(v);
                if constexpr (sizeof(TC) == 2)
                    C[(ll)(row + r) * ldc + col] = f2b(v);
                else
                    C[(ll)(row + r) * ldc + col] = v;
            }
        }
    }
}

// ---------------------------------------------------------------------------
// gemm2: pipelined MFMA bf16 GEMM (T3+T4+T5: counted vmcnt, never 0 in loop;
// triple-buffered LDS; one raw s_barrier per K-tile; setprio around MFMA).
//   BK=64, 512 threads = 8 waves; BM in {256,128}, BN in {128,64}.
// ---------------------------------------------------------------------------
template<int BM, int BN, int ACT, typename TC>
__global__ __launch_bounds__(512) void gemm2(
    const ushort* __restrict__ A, int lda, ll sA1, ll sA2,
    const ushort* __restrict__ B, int ldb, ll sB1, ll sB2,
    const float* __restrict__ bias, ll sb1, ll sb2,
    TC* __restrict__ C, int ldc, ll sC1, ll sC2,
    int K, int Z2, float alpha)
{
    constexpr int WR = BM / 64;          // waves along M (4 or 2)
    constexpr int WC = 8 / WR;           // 2 or 4
    constexpr int MI = 4;                // 64 rows per wave
    constexpr int NI = BN / WC / 16;     // 4 or 2
    constexpr int NH = NI / 2 ? NI / 2 : 1;  // frags per phase
    constexpr int LA = BM / 64;          // A stage instrs per K-tile
    constexpr int LB = BN / 64;          // B stage instrs per K-tile

    __shared__ alignas(16) ushort As[3][BM * 64];
    __shared__ alignas(16) ushort Bs[3][BN * 64];

    const int z1 = blockIdx.z / Z2, z2 = blockIdx.z % Z2;
    A += z1 * sA1 + z2 * sA2;
    B += z1 * sB1 + z2 * sB2;
    C += z1 * sC1 + z2 * sC2;

    const int t = threadIdx.x;
    const int lane = t & 63, wave = t >> 6;
    const int quad = lane >> 4, l16 = lane & 15;
    const int wm = wave / WC, wn = wave % WC;
    const int m0 = blockIdx.y * BM, n0 = blockIdx.x * BN;

    auto stageA = [&](int kt) {
        const ushort* src = A + (ll)m0 * lda + kt * 64;
        ushort* dst = As[kt % 3];
        #pragma unroll
        for (int j = 0; j < LA; j++) {
            int seg = j * 512 + t;
            int row = seg >> 3, kk = (seg & 7) * 8;
            gload16(src + (ll)row * lda + kk, dst + seg * 8);
        }
    };
    auto stageB = [&](int kt) {
        const ushort* src = B + (ll)n0 * ldb + kt * 64;
        ushort* dst = Bs[kt % 3];
        #pragma unroll
        for (int j = 0; j < LB; j++) {
            int seg = j * 512 + t;
            int row = seg >> 3, kk = (seg & 7) * 8;
            gload16(src + (ll)row * ldb + kk, dst + seg * 8);
        }
    };

    f32x4 acc[MI][NI] = {};
    const int NK = K / 64;

    stageA(0); stageB(0);
    if (NK > 1) { stageA(1); stageB(1); }

    for (int kt = 0; kt < NK; kt++) {
        if (kt + 1 < NK)
            asm volatile("s_waitcnt vmcnt(%0)" :: "n"(LA + LB) : "memory");
        else
            asm volatile("s_waitcnt vmcnt(0)" ::: "memory");
        __builtin_amdgcn_sched_barrier(0);
        __builtin_amdgcn_s_barrier();
        __builtin_amdgcn_sched_barrier(0);

        const ushort* Abuf = As[kt % 3];
        const ushort* Bbuf = Bs[kt % 3];

        // ---- phase 0: all A frags + first half of B frags, then MFMA ----
        short8 a[MI][2], b0[NH][2];
        #pragma unroll
        for (int mi = 0; mi < MI; mi++)
            #pragma unroll
            for (int kh = 0; kh < 2; kh++)
                a[mi][kh] = *reinterpret_cast<const short8*>(
                    &Abuf[(wm * 64 + mi * 16 + l16) * 64 + kh * 32 + quad * 8]);
        #pragma unroll
        for (int ni = 0; ni < NH; ni++)
            #pragma unroll
            for (int kh = 0; kh < 2; kh++)
                b0[ni][kh] = *reinterpret_cast<const short8*>(
                    &Bbuf[(wn * NI * 16 + ni * 16 + l16) * 64 + kh * 32 + quad * 8]);
        if (kt + 2 < NK) stageA(kt + 2);
        asm volatile("s_waitcnt lgkmcnt(0)" ::: "memory");
        __builtin_amdgcn_sched_barrier(0);
        __builtin_amdgcn_s_setprio(1);
        #pragma unroll
        for (int mi = 0; mi < MI; mi++)
            #pragma unroll
            for (int ni = 0; ni < NH; ni++)
                #pragma unroll
                for (int kh = 0; kh < 2; kh++)
                    acc[mi][ni] = __builtin_amdgcn_mfma_f32_16x16x32_bf16(
                        a[mi][kh], b0[ni][kh], acc[mi][ni], 0, 0, 0);
        __builtin_amdgcn_s_setprio(0);
        __builtin_amdgcn_sched_barrier(0);

        // ---- phase 1: second half of B frags, then MFMA ----
        short8 b1[NH][2];
        #pragma unroll
        for (int ni = 0; ni < NH; ni++)
            #pragma unroll
            for (int kh = 0; kh < 2; kh++)
                b1[ni][kh] = *reinterpret_cast<const short8*>(
                    &Bbuf[(wn * NI * 16 + (NH + ni) * 16 + l16) * 64 + kh * 32 + quad * 8]);
        if (kt + 2 < NK) stageB(kt + 2);
        asm volatile("s_waitcnt lgkmcnt(0)" ::: "memory");
        __builtin_amdgcn_sched_barrier(0);
        __builtin_amdgcn_s_setprio(1);
        #pragma unroll
        for (int mi = 0; mi < MI; mi++)
            #pragma unroll
            for (int ni = 0; ni < NH; ni++)
                #pragma unroll
                for (int kh = 0; kh < 2; kh++)
                    acc[mi][NH + ni] = __builtin_amdgcn_mfma_f32_16x16x32_bf16(
                        a[mi][kh], b1[ni][kh], acc[mi][NH + ni], 0, 0, 0);
        __builtin_amdgcn_s_setprio(0);
        __builtin_amdgcn_sched_barrier(0);
    }

    const float* bz = bias ? (bias + z1 * sb1 + z2 * sb2) : nullptr;
    #pragma unroll
    for (int mi = 0; mi < MI; mi++) {
        #pragma unroll
        for (int ni = 0; ni < NI; ni++) {
            const int row = m0 + wm * 64 + mi * 16 + quad * 4;
            const int col = n0 + wn * NI * 16 + ni * 16 + l16;
            const float bv = bz ? bz[col] : 0.f;
            #pragma unroll
            for (int r = 0; r < 4; r++) {
                float v = alpha * acc[mi][ni][r] + bv;
                if (ACT) v = gelu_f(v);
                if constexpr (sizeof(TC) == 2)
                    C[(ll)(row + r) * ldc + col] = f2b(v);
                else
                    C[(ll)(row + r) * ldc + col] = v;
            }
        }
    }
}

// ---------------------------------------------------------------------------
// Attention softmax over m, v3 (unchanged).
// ---------------------------------------------------------------------------
__global__ __launch_bounds__(256) void attn_softmax(
    ushort* __restrict__ p, float* __restrict__ attn_out)
{
    __shared__ float tile[16][1024];
    const int n = blockIdx.x, b = blockIdx.y;
    const int t = threadIdx.x;
    const int lane = t & 63, w = t >> 6;
    ushort* base = p + ((ll)(b * SEQ + n) * HEADS) * SEQ;
    #pragma unroll 1
    for (int g = 0; g < 4; g++) {
        const int h = g * 4 + w;
        ushort* row = base + (ll)h * SEQ + lane * 16;
        uint4 r0 = reinterpret_cast<const uint4*>(row)[0];
        uint4 r1 = reinterpret_cast<const uint4*>(row)[1];
        uint rr[8] = {r0.x, r0.y, r0.z, r0.w, r1.x, r1.y, r1.z, r1.w};
        float v[16];
        float m = -3.0e38f;
        #pragma unroll
        for (int j = 0; j < 8; j++) {
            v[2 * j]     = b2f((ushort)(rr[j] & 0xFFFFu));
            v[2 * j + 1] = b2f((ushort)(rr[j] >> 16));
            m = fmaxf(m, fmaxf(v[2 * j], v[2 * j + 1]));
        }
        #pragma unroll
        for (int o = 32; o; o >>= 1) m = fmaxf(m, __shfl_xor(m, o));
        float s = 0.f;
        #pragma unroll
        for (int j = 0; j < 16; j++) { v[j] = __expf(v[j] - m); s += v[j]; }
        #pragma unroll
        for (int o = 32; o; o >>= 1) s += __shfl_xor(s, o);
        const float inv = 1.f / s;
        #pragma unroll
        for (int j = 0; j < 16; j++) v[j] *= inv;
        uint pw[8];
        #pragma unroll
        for (int j = 0; j < 8; j++) pw[j] = pk(v[2 * j], v[2 * j + 1]);
        uint4 w0, w1;
        w0.x = pw[0]; w0.y = pw[1]; w0.z = pw[2]; w0.w = pw[3];
        w1.x = pw[4]; w1.y = pw[5]; w1.z = pw[6]; w1.w = pw[7];
        reinterpret_cast<uint4*>(row)[0] = w0;
        reinterpret_cast<uint4*>(row)[1] = w1;
        #pragma unroll
        for (int jj = 0; jj < 4; jj++) {
            float4 f4;
            f4.x = v[4 * jj]; f4.y = v[4 * jj + 1];
            f4.z = v[4 * jj + 2]; f4.w = v[4 * jj + 3];
            *reinterpret_cast<float4*>(&tile[h][(jj * 64 + lane) * 4]) = f4;
        }
    }
    __syncthreads();
    float* outp = attn_out + ((ll)b * SEQ + n) * SEQ * HEADS;
    #pragma unroll
    for (int jj = 0; jj < 4; jj++) {
        const int mm = t + 256 * jj;
        const int gm = mm >> 2;
        const int fi = ((gm & 3) * 64 + (gm >> 2)) * 4 + (mm & 3);
        float o16[16];
        #pragma unroll
        for (int h = 0; h < 16; h++) o16[h] = tile[h][fi];
        float4* dst = reinterpret_cast<float4*>(outp + (ll)mm * HEADS);
        #pragma unroll
        for (int q = 0; q < 4; q++) {
            float4 o4;
            o4.x = o16[4 * q]; o4.y = o16[4 * q + 1];
            o4.z = o16[4 * q + 2]; o4.w = o16[4 * q + 3];
            dst[q] = o4;
        }
    }
}

// ---------------------------------------------------------------------------
// LayerNorm (vectorized), optional bf16 copy.
// ---------------------------------------------------------------------------
__global__ __launch_bounds__(256) void ln_kernel(
    const float* __restrict__ a, const float* __restrict__ b, float coef,
    const float* __restrict__ g, const float* __restrict__ beta,
    float* __restrict__ out, ushort* __restrict__ out_bf)
{
    const int row = blockIdx.x;
    const int t = threadIdx.x;
    float4 av = reinterpret_cast<const float4*>(a + (ll)row * DIM)[t];
    float4 bv = reinterpret_cast<const float4*>(b + (ll)row * DIM)[t];
    float4 v;
    v.x = av.x + coef * bv.x; v.y = av.y + coef * bv.y;
    v.z = av.z + coef * bv.z; v.w = av.w + coef * bv.w;
    float s1 = v.x + v.y + v.z + v.w;
    float s2 = v.x * v.x + v.y * v.y + v.z * v.z + v.w * v.w;
    __shared__ float red[8];
    #pragma unroll
    for (int o = 32; o; o >>= 1) { s1 += __shfl_xor(s1, o); s2 += __shfl_xor(s2, o); }
    int w = t >> 6;
    if ((t & 63) == 0) { red[w] = s1; red[4 + w] = s2; }
    __syncthreads();
    s1 = red[0] + red[1] + red[2] + red[3];
    s2 = red[4] + red[5] + red[6] + red[7];
    float mu = s1 * (1.f / DIM);
    float var = s2 * (1.f / DIM) - mu * mu;
    float rs = rsqrtf(var + LNEPS);
    float4 gv = reinterpret_cast<const float4*>(g)[t];
    float4 be = reinterpret_cast<const float4*>(beta)[t];
    float4 o;
    o.x = (v.x - mu) * rs * gv.x + be.x;
    o.y = (v.y - mu) * rs * gv.y + be.y;
    o.z = (v.z - mu) * rs * gv.z + be.z;
    o.w = (v.w - mu) * rs * gv.w + be.w;
    reinterpret_cast<float4*>(out + (ll)row * DIM)[t] = o;
    if (out_bf) {
        us4 hv;
        hv.x = f2b(o.x); hv.y = f2b(o.y); hv.z = f2b(o.z); hv.w = f2b(o.w);
        reinterpret_cast<us4*>(out_bf + (ll)row * DIM)[t] = hv;
    }
}

// ---------------------------------------------------------------------------
// row softmax over 1024 contiguous fp32 -> bf16 out.  Used for combine
// (rows = tokens) AND for dispatch (rows = (b,es) of transposed logits).
// float4 loads, us4 stores; 4096 blocks.
// ---------------------------------------------------------------------------
__global__ __launch_bounds__(256) void row_softmax(
    const float* __restrict__ logits, ushort* __restrict__ comb)
{
    const int row = blockIdx.x;
    const int t = threadIdx.x;
    float4 v = reinterpret_cast<const float4*>(logits + (ll)row * 1024)[t];
    float m = fmaxf(fmaxf(v.x, v.y), fmaxf(v.z, v.w));
    __shared__ float red[8];
    #pragma unroll
    for (int o = 32; o; o >>= 1) m = fmaxf(m, __shfl_xor(m, o));
    int w = t >> 6;
    if ((t & 63) == 0) red[w] = m;
    __syncthreads();
    m = fmaxf(fmaxf(red[0], red[1]), fmaxf(red[2], red[3]));
    __syncthreads();
    float4 e;
    e.x = __expf(v.x - m); e.y = __expf(v.y - m);
    e.z = __expf(v.z - m); e.w = __expf(v.w - m);
    float s = e.x + e.y + e.z + e.w;
    #pragma unroll
    for (int o = 32; o; o >>= 1) s += __shfl_xor(s, o);
    if ((t & 63) == 0) red[4 + w] = s;
    __syncthreads();
    s = red[4] + red[5] + red[6] + red[7];
    float inv = 1.f / s;
    us4 hv;
    hv.x = f2b(e.x * inv); hv.y = f2b(e.y * inv);
    hv.z = f2b(e.z * inv); hv.w = f2b(e.w * inv);
    reinterpret_cast<us4*>(comb + (ll)row * 1024)[t] = hv;
}

// ---------------------------------------------------------------------------
extern "C" void kernel_launch(void* const* d_in, const int* in_sizes, int n_in,
                              void* d_out, int out_size, void* d_ws, size_t ws_size,
                              hipStream_t stream)
{
    const float* x   = (const float*)d_in[0];
    const float* Wq  = (const float*)d_in[1];
    const float* bq  = (const float*)d_in[2];
    const float* Wkv = (const float*)d_in[3];
    const float* bkv = (const float*)d_in[4];
    const float* Wp  = (const float*)d_in[5];
    const float* bp  = (const float*)d_in[6];
    const float* g1  = (const float*)d_in[7];
    const float* b1  = (const float*)d_in[8];
    const float* phi = (const float*)d_in[9];
    const float* We1 = (const float*)d_in[10];
    const float* be1 = (const float*)d_in[11];
    const float* We2 = (const float*)d_in[12];
    const float* be2 = (const float*)d_in[13];
    const float* g2  = (const float*)d_in[14];
    const float* b2  = (const float*)d_in[15];

    float* out_y    = (float*)d_out;
    float* out_attn = out_y + (ll)BATCH * SEQ * DIM;

    // Workspace layout (float offsets, M1 = 1M floats).  Peak ~46.5M fl = 186 MB.
    // Aliases: po/logitT <- p_bf head (dead after AV); moe <- x_bf/W*T;
    // We1T/We2T <- qkv_bf/vT; ymoeT <- ao_bf.
    const ll M1 = 1024 * 1024;
    float*  ws     = (float*)d_ws;
    ushort* x_bf   = (ushort*)(ws);                 // [0, 2M)
    ushort* WqkvT  = (ushort*)(ws + 2 * M1);        // [2, 3.5M)   3072x1024 bf16
    ushort* WpT    = (ushort*)(ws + 7 * M1 / 2);    // [3.5, 4M)
    ushort* phiT   = (ushort*)(ws + 4 * M1);        // [4, 4.5M)
    ushort* qkv_bf = (ushort*)(ws + 9 * M1 / 2);    // [4.5, 10.5M) 4096x3072 bf16
    ushort* vT     = (ushort*)(ws + 21 * M1 / 2);   // [10.5, 12.5M)
    ushort* p_bf   = (ushort*)(ws + 25 * M1 / 2);   // [12.5, 44.5M)
    float*  po     = ws + 25 * M1 / 2;              //   (after AV)
    float*  logitT = ws + 25 * M1 / 2;              //   (after LN; 4M fp32)
    ushort* ao_bf  = (ushort*)(ws + 89 * M1 / 2);   // [44.5, 46.5M)
    ushort* ymoeT  = (ushort*)(ws + 89 * M1 / 2);   //   (phase 2 alias)
    float*  x1     = ws + 33 * M1 / 2;              // [16.5, 20.5M)
    ushort* x1_bf  = (ushort*)(ws + 41 * M1 / 2);   // [20.5, 22.5M)
    ushort* x1T    = (ushort*)(ws + 45 * M1 / 2);   // [22.5, 24.5M)
    float*  logit  = ws + 49 * M1 / 2;              // [24.5, 28.5M)
    ushort* dispT  = (ushort*)(ws + 57 * M1 / 2);   // [28.5, 30.5M)
    ushort* comb   = (ushort*)(ws + 61 * M1 / 2);   // [30.5, 32.5M)
    ushort* slots  = (ushort*)(ws + 65 * M1 / 2);   // [32.5, 34.5M)
    ushort* hmid   = (ushort*)(ws + 69 * M1 / 2);   // [34.5, 42.5M)
    ushort* ymoe   = (ushort*)(ws + 85 * M1 / 2);   // [42.5, 44.5M)
    ushort* We1T   = (ushort*)(ws + 9 * M1 / 2);    // [4.5, 8.5M)  phase 2
    ushort* We2T   = (ushort*)(ws + 17 * M1 / 2);   // [8.5, 12.5M) phase 2
    float*  bqkv   = ws + 93 * M1 / 2;              // [46.5M, +3072)
    float*  moe    = ws;                            // [0, 4M) phase 2

    dim3 blk(256), blk5(512);

    // 0: bf16 conversions / weight transposes for the attention phase
    cvt_bf16<<<dim3(2048), blk, 0, stream>>>(x, x_bf);
    transpose_cvt<float,ushort><<<dim3(16, 16, 1), blk, 0, stream>>>(
        Wq, DIM, 0, 0, WqkvT, DIM, 0, 0, 1);
    transpose_cvt<float,ushort><<<dim3(32, 16, 1), blk, 0, stream>>>(
        Wkv, 2 * DIM, 0, 0, WqkvT + (ll)DIM * DIM, DIM, 0, 0, 1);
    transpose_cvt<float,ushort><<<dim3(16, 16, 1), blk, 0, stream>>>(
        Wp, DIM, 0, 0, WpT, DIM, 0, 0, 1);
    transpose_cvt<float,ushort><<<dim3(16, 16, 1), blk, 0, stream>>>(
        phi, ES, 0, 0, phiT, DIM, 0, 0, 1);
    concat_bias<<<dim3(12), blk, 0, stream>>>(bq, bkv, bqkv);

    // 1: fused QKV projection (N=3072, bf16 out)  [pipelined 256x128]
    gemm2<256,128,0,ushort><<<dim3(24, 16, 1), blk5, 0, stream>>>(
        x_bf, DIM, 0, 0, WqkvT, DIM, 0, 0, bqkv, 0, 0,
        qkv_bf, 3 * DIM, 0, 0, DIM, 1, 1.f);

    // 2: vT[b,h][d][m] <- v slice of qkv
    transpose_cvt<ushort,ushort><<<dim3(1, 16, BATCH * HEADS), blk, 0, stream>>>(
        qkv_bf + 2 * DIM, 3 * DIM, (ll)SEQ * 3 * DIM, HD,
        vT, SEQ, (ll)HEADS * HD * SEQ, (ll)HD * SEQ, HEADS);

    // 3: scores p[b,n,h,m] = 0.125 * q_bh @ k_bh^T  (K=64: m97 kernel)
    gemm_bf16<2,2,4,4,0,ushort><<<dim3(8, 8, BATCH * HEADS), blk, 0, stream>>>(
        qkv_bf, 3 * DIM, (ll)SEQ * 3 * DIM, HD,
        qkv_bf + DIM, 3 * DIM, (ll)SEQ * 3 * DIM, HD,
        nullptr, 0, 0,
        p_bf, HEADS * SEQ, (ll)SEQ * HEADS * SEQ, (ll)SEQ,
        HD, HEADS, 0.125f);

    // 4: softmax over m (in-place bf16) + fp32 bnmh attn output
    attn_softmax<<<dim3(SEQ, BATCH), blk, 0, stream>>>(p_bf, out_attn);

    // 5: ao = p_bh @ vT_bh^T   [pipelined 256x64, NK=16]
    gemm2<256,64,0,ushort><<<dim3(1, 4, BATCH * HEADS), blk5, 0, stream>>>(
        p_bf, HEADS * SEQ, (ll)SEQ * HEADS * SEQ, (ll)SEQ,
        vT, SEQ, (ll)HEADS * HD * SEQ, (ll)HD * SEQ,
        nullptr, 0, 0,
        ao_bf, DIM, (ll)SEQ * DIM, HD,
        SEQ, HEADS, 1.f);

    // 6: output projection (fp32 out)  [pipelined 128x128]
    gemm2<128,128,0,float><<<dim3(8, 32, 1), blk5, 0, stream>>>(
        ao_bf, DIM, 0, 0, WpT, DIM, 0, 0, bp, 0, 0,
        po, DIM, 0, 0, DIM, 1, 1.f);
    // 7: x1 = LN(po + x)
    ln_kernel<<<dim3(NTOK), blk, 0, stream>>>(po, x, 1.0f, g1, b1, x1, x1_bf);

    // 7b: MoE weight transposes + x1T
    transpose_cvt<float,ushort><<<dim3(64, 16, 2), blk, 0, stream>>>(
        We1, HID, 0, (ll)DIM * HID, We1T, DIM, 0, (ll)HID * DIM, 2);
    transpose_cvt<float,ushort><<<dim3(16, 64, 2), blk, 0, stream>>>(
        We2, DIM, 0, (ll)HID * DIM, We2T, HID, 0, (ll)DIM * HID, 2);
    transpose_cvt<ushort,ushort><<<dim3(16, 16, BATCH), blk, 0, stream>>>(
        x1_bf, DIM, (ll)SEQ * DIM, 0, x1T, SEQ, (ll)DIM * SEQ, 0, 1);

    // 8: moe logits = x1 @ phi (fp32 out)  [pipelined 128x128]
    gemm2<128,128,0,float><<<dim3(8, 32, 1), blk5, 0, stream>>>(
        x1_bf, DIM, 0, 0, phiT, DIM, 0, 0, nullptr, 0, 0,
        logit, ES, 0, 0, DIM, 1, 1.f);

    // 9: dispatch softmax over n — coalesced: transpose logits to
    //    logitT[b][es][n] (fp32), then contiguous row softmax -> bf16 dispT.
    transpose_cvt<float,float><<<dim3(16, 16, BATCH), blk, 0, stream>>>(
        logit, ES, (ll)SEQ * ES, 0, logitT, SEQ, (ll)ES * SEQ, 0, 1);
    row_softmax<<<dim3(BATCH * ES), blk, 0, stream>>>(logitT, dispT);
    // 10: combine softmax over es (contiguous rows)
    row_softmax<<<dim3(NTOK), blk, 0, stream>>>(logit, comb);

    // 11: slots[b] = dispT[b] @ x1T[b]^T   [pipelined 128x128]
    gemm2<128,128,0,ushort><<<dim3(8, 8, BATCH), blk5, 0, stream>>>(
        dispT, SEQ, (ll)ES * SEQ, 0,
        x1T, SEQ, (ll)DIM * SEQ, 0,
        nullptr, 0, 0,
        slots, DIM, (ll)ES * DIM, 0,
        SEQ, 1, 1.f);

    // 12: hmid = gelu(slots @ We1 + be1)   [pipelined 256x128]
    gemm2<256,128,1,ushort><<<dim3(32, 2, BATCH * NEXP), blk5, 0, stream>>>(
        slots, DIM, (ll)ES * DIM, (ll)NSLOT * DIM,
        We1T, DIM, 0, (ll)HID * DIM,
        be1, 0, HID,
        hmid, HID, (ll)ES * HID, (ll)NSLOT * HID,
        DIM, NEXP, 1.f);

    // 13: ymoe = hmid @ We2 + be2   [pipelined 128x128]
    gemm2<128,128,0,ushort><<<dim3(8, 4, BATCH * NEXP), blk5, 0, stream>>>(
        hmid, HID, (ll)ES * HID, (ll)NSLOT * HID,
        We2T, HID, 0, (ll)DIM * HID,
        be2, 0, DIM,
        ymoe, DIM, (ll)ES * DIM, (ll)NSLOT * DIM,
        HID, NEXP, 1.f);

    // 13b: ymoeT[b][d][es] <- ymoe
    transpose_cvt<ushort,ushort><<<dim3(16, 16, BATCH), blk, 0, stream>>>(
        ymoe, DIM, (ll)ES * DIM, 0, ymoeT, ES, (ll)DIM * ES, 0, 1);

    // 14: moe[b] = comb[b] @ ymoeT[b]^T   [pipelined 128x128]
    gemm2<128,128,0,float><<<dim3(8, 8, BATCH), blk5, 0, stream>>>(
        comb, ES, (ll)SEQ * ES, 0,
        ymoeT, ES, (ll)DIM * ES, 0,
        nullptr, 0, 0,
        moe, DIM, (ll)SEQ * DIM, 0,
        ES, 1, 1.f);

    // 15: y = LN(moe + 2*x1)
    ln_kernel<<<dim3(NTOK), blk, 0, stream>>>(moe, x1, 2.0f, g2, b2, out_y, nullptr);
}